// Round 2
// baseline (756.704 us; speedup 1.0000x reference)
//
#include <hip/hip_runtime.h>
#include <hip/hip_bf16.h>

typedef __attribute__((ext_vector_type(4))) float f32x4;
typedef __attribute__((ext_vector_type(8))) short s16x8;
typedef __attribute__((ext_vector_type(4))) float f4v;
typedef __attribute__((ext_vector_type(4))) unsigned short us4;
typedef unsigned short u16;
typedef unsigned int u32;

#define H_ 12
#define NTOK 4096
#define DHEAD 64
#define MFEAT 256
#define CDIM 768

#define NORMALIZER 0.35355339059327373f  /* 64^-0.25 */
#define DIAGSCALE 0.0625f                /* 0.5 * NORMALIZER^2 */
#define RATIO_ 0.0625f                   /* 256^-0.5 */
#define EPS_ 1e-4f

#define MFMA(a, b, c) __builtin_amdgcn_mfma_f32_16x16x32_bf16((a), (b), (c), 0, 0, 0)

__device__ __forceinline__ float bf2f(u16 u) {
  union { float f; u32 v; } x; x.v = ((u32)u) << 16; return x.f;
}
__device__ __forceinline__ u16 f2bf(float f) {
  union { float f; u32 v; } x; x.f = f;
  u32 v = x.v + 0x7FFFu + ((x.v >> 16) & 1u);
  return (u16)(v >> 16);
}
__device__ __forceinline__ u32 fenc(float f) {
  u32 u = __float_as_uint(f);
  return (u & 0x80000000u) ? ~u : (u | 0x80000000u);
}
__device__ __forceinline__ float fdec(u32 k) {
  u32 u = (k & 0x80000000u) ? (k & 0x7fffffffu) : ~k;
  return __uint_as_float(u);
}

// write a wave's staged 64x64 bf16 tile (rows padded to 72) to dst
__device__ __forceinline__ void st_write64(const u16* stw, u16* dst, long ld, int lane) {
  int r0 = lane >> 3, cc = lane & 7;
#pragma unroll
  for (int c = 0; c < 8; ++c) {
    int row = c * 8 + r0;
    s16x8 v = *(const s16x8*)(stw + row * 72 + cc * 8);
    *(s16x8*)(dst + (long)row * ld + cc * 8) = v;
  }
}

__global__ void k_init(u32* mk) {
  if (threadIdx.x < 8) mk[threadIdx.x] = 0u;
}

__global__ void cvt_bf16(const float* __restrict__ in, u16* __restrict__ out, int n4) {
  int i = blockIdx.x * 256 + threadIdx.x;
  if (i >= n4) return;
  f4v v = *(const f4v*)(in + (long)i * 4);
  us4 o;
#pragma unroll
  for (int j = 0; j < 4; ++j) o[j] = f2bf(v[j]);
  *(us4*)(out + (long)i * 4) = o;
}

// ---------------- K0: QKV GEMM (NT, 128x128 tile) + split epilogue ----------------
__global__ __launch_bounds__(256) void k0_qkv(const u16* __restrict__ A, const u16* __restrict__ Bm,
                                              u16* __restrict__ qb, u16* __restrict__ kb,
                                              u16* __restrict__ vT) {
  __shared__ u16 smem[4 * 64 * 72];
  u16* lA = smem;
  u16* lB = smem + 5120;
  int tid = threadIdx.x, lane = tid & 63, wid = tid >> 6;
  int wr = (wid >> 1) << 6, wc = (wid & 1) << 6;
  int srow = tid >> 2, sch = tid & 3;
  int l15 = lane & 15, lk = lane >> 4;
  int m0 = blockIdx.x << 7, n0 = blockIdx.y << 7;
  const u16* Ab = A + (long)m0 * CDIM;
  const u16* Bb = Bm + (long)n0 * CDIM;
  f32x4 acc[4][4];
#pragma unroll
  for (int i = 0; i < 4; ++i)
#pragma unroll
    for (int j = 0; j < 4; ++j) acc[i][j] = (f32x4){0.f, 0.f, 0.f, 0.f};
  for (int k0 = 0; k0 < CDIM; k0 += 32) {
    __syncthreads();
    *(s16x8*)(lA + srow * 40 + sch * 8) = *(const s16x8*)(Ab + (long)srow * CDIM + k0 + sch * 8);
    *(s16x8*)(lA + (srow + 64) * 40 + sch * 8) = *(const s16x8*)(Ab + (long)(srow + 64) * CDIM + k0 + sch * 8);
    *(s16x8*)(lB + srow * 40 + sch * 8) = *(const s16x8*)(Bb + (long)srow * CDIM + k0 + sch * 8);
    *(s16x8*)(lB + (srow + 64) * 40 + sch * 8) = *(const s16x8*)(Bb + (long)(srow + 64) * CDIM + k0 + sch * 8);
    __syncthreads();
    s16x8 af[4], bv[4];
#pragma unroll
    for (int i = 0; i < 4; ++i) {
      af[i] = *(const s16x8*)(lA + (wr + i * 16 + l15) * 40 + lk * 8);
      bv[i] = *(const s16x8*)(lB + (wc + i * 16 + l15) * 40 + lk * 8);
    }
#pragma unroll
    for (int i = 0; i < 4; ++i)
#pragma unroll
      for (int j = 0; j < 4; ++j) acc[i][j] = MFMA(af[i], bv[j], acc[i][j]);
  }
  __syncthreads();
  int colbase = n0 + wc;
  int qi = colbase / CDIM;
  int h = (colbase % CDIM) >> 6;
  int rowbase = m0 + wr;
  int b = rowbase >> 12;
  int nloc = rowbase & (NTOK - 1);
  u16* stw = smem + wid * 64 * 72;
  if (qi < 2) {
#pragma unroll
    for (int i = 0; i < 4; ++i)
#pragma unroll
      for (int j = 0; j < 4; ++j)
#pragma unroll
        for (int r = 0; r < 4; ++r)
          stw[(i * 16 + lk * 4 + r) * 72 + j * 16 + l15] = f2bf(acc[i][j][r]);
    u16* dst = (qi == 0 ? qb : kb) + ((long)(b * H_ + h) * NTOK + nloc) * DHEAD;
    st_write64(stw, dst, DHEAD, lane);
  } else {
#pragma unroll
    for (int i = 0; i < 4; ++i)
#pragma unroll
      for (int j = 0; j < 4; ++j)
#pragma unroll
        for (int r = 0; r < 4; ++r)
          stw[(j * 16 + l15) * 72 + i * 16 + lk * 4 + r] = f2bf(acc[i][j][r]);
    u16* dst = vT + (long)(b * H_ + h) * DHEAD * NTOK + nloc;
    st_write64(stw, dst, NTOK, lane);
  }
}

// ---------------- K2q: phi(q) for one token-quarter ----------------
__global__ __launch_bounds__(256) void k2_q(const u16* __restrict__ qb, const u16* __restrict__ projb,
                                            u16* __restrict__ qpQ, int qtr) {
  __shared__ u16 st[4 * 64 * 72];
  __shared__ float rowmax[4][64];
  __shared__ float diagv[64];
  int bh = blockIdx.y;
  int n0 = blockIdx.x << 6;  // local within quarter [0,1024)
  const u16* Aq = qb + ((long)bh * NTOK + qtr * 1024 + n0) * DHEAD;
  int tid = threadIdx.x, lane = tid & 63, wid = tid >> 6;
  int wc = wid << 6;
  int l15 = lane & 15, lk = lane >> 4;
  f32x4 acc[4][4];
#pragma unroll
  for (int i = 0; i < 4; ++i)
#pragma unroll
    for (int j = 0; j < 4; ++j) acc[i][j] = (f32x4){0.f, 0.f, 0.f, 0.f};
  float ss[4] = {0.f, 0.f, 0.f, 0.f};
#pragma unroll
  for (int ks = 0; ks < 2; ++ks) {
    s16x8 a[4], bv[4];
#pragma unroll
    for (int i = 0; i < 4; ++i)
      a[i] = *(const s16x8*)(Aq + (long)(i * 16 + l15) * DHEAD + ks * 32 + lk * 8);
#pragma unroll
    for (int j = 0; j < 4; ++j)
      bv[j] = *(const s16x8*)(projb + (long)(wc + j * 16 + l15) * DHEAD + ks * 32 + lk * 8);
#pragma unroll
    for (int i = 0; i < 4; ++i)
#pragma unroll
      for (int e = 0; e < 8; ++e) { float f = bf2f((u16)a[i][e]); ss[i] += f * f; }
#pragma unroll
    for (int i = 0; i < 4; ++i)
#pragma unroll
      for (int j = 0; j < 4; ++j) acc[i][j] = MFMA(a[i], bv[j], acc[i][j]);
  }
#pragma unroll
  for (int i = 0; i < 4; ++i) {
    float s = ss[i];
    s += __shfl_xor(s, 16);
    s += __shfl_xor(s, 32);
    if (wid == 0 && lk == 0) diagv[i * 16 + l15] = s * DIAGSCALE;
  }
#pragma unroll
  for (int i = 0; i < 4; ++i)
#pragma unroll
    for (int r = 0; r < 4; ++r) {
      float m = fmaxf(fmaxf(acc[i][0][r], acc[i][1][r]), fmaxf(acc[i][2][r], acc[i][3][r]));
      m = fmaxf(m, __shfl_xor(m, 1));
      m = fmaxf(m, __shfl_xor(m, 2));
      m = fmaxf(m, __shfl_xor(m, 4));
      m = fmaxf(m, __shfl_xor(m, 8));
      if (l15 == 0) rowmax[wid][i * 16 + lk * 4 + r] = m;
    }
  __syncthreads();
  u16* stw = st + wid * 64 * 72;
#pragma unroll
  for (int i = 0; i < 4; ++i)
#pragma unroll
    for (int r = 0; r < 4; ++r) {
      int row = i * 16 + lk * 4 + r;
      float m = fmaxf(fmaxf(rowmax[0][row], rowmax[1][row]),
                      fmaxf(rowmax[2][row], rowmax[3][row])) * NORMALIZER;
      float dg = diagv[row];
#pragma unroll
      for (int j = 0; j < 4; ++j) {
        float v = RATIO_ * (__expf(acc[i][j][r] * NORMALIZER - dg - m) + EPS_);
        stw[row * 72 + j * 16 + l15] = f2bf(v);
      }
    }
  u16* dst = qpQ + ((long)bh * 1024 + n0) * MFEAT + wc;
  st_write64(stw, dst, MFEAT, lane);
}

// ---------------- K2k pass1: global max of k_dash per batch ----------------
__global__ __launch_bounds__(256) void k2_k1(const u16* __restrict__ kb, const u16* __restrict__ projb,
                                             u32* __restrict__ mk) {
  __shared__ float wmax[4];
  int bh = blockIdx.y;
  int n0 = blockIdx.x << 6;
  const u16* Aq = kb + ((long)bh * NTOK + n0) * DHEAD;
  int tid = threadIdx.x, lane = tid & 63, wid = tid >> 6;
  int wc = wid << 6;
  int l15 = lane & 15, lk = lane >> 4;
  f32x4 acc[4][4];
#pragma unroll
  for (int i = 0; i < 4; ++i)
#pragma unroll
    for (int j = 0; j < 4; ++j) acc[i][j] = (f32x4){0.f, 0.f, 0.f, 0.f};
#pragma unroll
  for (int ks = 0; ks < 2; ++ks) {
    s16x8 a[4], bv[4];
#pragma unroll
    for (int i = 0; i < 4; ++i)
      a[i] = *(const s16x8*)(Aq + (long)(i * 16 + l15) * DHEAD + ks * 32 + lk * 8);
#pragma unroll
    for (int j = 0; j < 4; ++j)
      bv[j] = *(const s16x8*)(projb + (long)(wc + j * 16 + l15) * DHEAD + ks * 32 + lk * 8);
#pragma unroll
    for (int i = 0; i < 4; ++i)
#pragma unroll
      for (int j = 0; j < 4; ++j) acc[i][j] = MFMA(a[i], bv[j], acc[i][j]);
  }
  float m = -3.4e38f;
#pragma unroll
  for (int i = 0; i < 4; ++i)
#pragma unroll
    for (int j = 0; j < 4; ++j)
#pragma unroll
      for (int r = 0; r < 4; ++r) m = fmaxf(m, acc[i][j][r]);
  m = fmaxf(m, __shfl_xor(m, 1));
  m = fmaxf(m, __shfl_xor(m, 2));
  m = fmaxf(m, __shfl_xor(m, 4));
  m = fmaxf(m, __shfl_xor(m, 8));
  m = fmaxf(m, __shfl_xor(m, 16));
  m = fmaxf(m, __shfl_xor(m, 32));
  if (lane == 0) wmax[wid] = m;
  __syncthreads();
  if (tid == 0) {
    float mm = fmaxf(fmaxf(wmax[0], wmax[1]), fmaxf(wmax[2], wmax[3])) * NORMALIZER;
    atomicMax(mk + (blockIdx.y / H_), fenc(mm));
  }
}

// ---------------- K3f: fused phi(k) + context = k'^T @ v  (per 1024-token chunk) ----------------
__global__ __launch_bounds__(256) void k3f(const u16* __restrict__ kb, const u16* __restrict__ vT,
                                           const u16* __restrict__ projb, const u32* __restrict__ mk,
                                           float* __restrict__ ctx4, float* __restrict__ kpart) {
  __shared__ u16 kT[256 * 72];   // k'^T tile [m][tok], wave-quadrant disjoint
  __shared__ float diagv[64];
  int bh = blockIdx.y, nc = blockIdx.x;  // nc in [0,4)
  int tid = threadIdx.x, lane = tid & 63, wid = tid >> 6;
  int l15 = lane & 15, lk = lane >> 4;
  int wc = wid << 6;
  float mg = fdec(mk[bh / H_]);
  const u16* Kb = kb + ((long)bh * NTOK + nc * 1024) * DHEAD;
  const u16* Vb = vT + (long)bh * DHEAD * NTOK + nc * 1024;
  f32x4 ctx[4][4];
#pragma unroll
  for (int i = 0; i < 4; ++i)
#pragma unroll
    for (int j = 0; j < 4; ++j) ctx[i][j] = (f32x4){0.f, 0.f, 0.f, 0.f};
  float cs[4] = {0.f, 0.f, 0.f, 0.f};
  for (int sb = 0; sb < 16; ++sb) {
    const u16* Ksb = Kb + sb * 64 * DHEAD;
    f32x4 acc[4][4];
#pragma unroll
    for (int i = 0; i < 4; ++i)
#pragma unroll
      for (int j = 0; j < 4; ++j) acc[i][j] = (f32x4){0.f, 0.f, 0.f, 0.f};
    float ss[4] = {0.f, 0.f, 0.f, 0.f};
#pragma unroll
    for (int ks = 0; ks < 2; ++ks) {
      s16x8 a[4], bv[4];
#pragma unroll
      for (int i = 0; i < 4; ++i)
        a[i] = *(const s16x8*)(Ksb + (long)(i * 16 + l15) * DHEAD + ks * 32 + lk * 8);
#pragma unroll
      for (int j = 0; j < 4; ++j)
        bv[j] = *(const s16x8*)(projb + (long)(wc + j * 16 + l15) * DHEAD + ks * 32 + lk * 8);
#pragma unroll
      for (int i = 0; i < 4; ++i)
#pragma unroll
        for (int e = 0; e < 8; ++e) { float f = bf2f((u16)a[i][e]); ss[i] += f * f; }
#pragma unroll
      for (int i = 0; i < 4; ++i)
#pragma unroll
        for (int j = 0; j < 4; ++j) acc[i][j] = MFMA(a[i], bv[j], acc[i][j]);
    }
#pragma unroll
    for (int i = 0; i < 4; ++i) {
      float s = ss[i];
      s += __shfl_xor(s, 16);
      s += __shfl_xor(s, 32);
      if (wid == 0 && lk == 0) diagv[i * 16 + l15] = s * DIAGSCALE;
    }
    __syncthreads();  // diag ready; prev kT reads done
#pragma unroll
    for (int i = 0; i < 4; ++i)
#pragma unroll
      for (int r = 0; r < 4; ++r) {
        int tok = i * 16 + lk * 4 + r;
        float dg = diagv[tok];
#pragma unroll
        for (int j = 0; j < 4; ++j) {
          float v = RATIO_ * (__expf(acc[i][j][r] * NORMALIZER - dg - mg) + EPS_);
          cs[j] += v;
          kT[(wc + j * 16 + l15) * 72 + tok] = f2bf(v);
        }
      }
    __syncthreads();  // kT ready
#pragma unroll
    for (int ks = 0; ks < 2; ++ks) {
      s16x8 a2[4], b2[4];
#pragma unroll
      for (int i = 0; i < 4; ++i)
        a2[i] = *(const s16x8*)(kT + (wc + i * 16 + l15) * 72 + ks * 32 + lk * 8);
#pragma unroll
      for (int j = 0; j < 4; ++j)
        b2[j] = *(const s16x8*)(Vb + (long)(j * 16 + l15) * NTOK + sb * 64 + ks * 32 + lk * 8);
#pragma unroll
      for (int i = 0; i < 4; ++i)
#pragma unroll
        for (int j = 0; j < 4; ++j) ctx[i][j] = MFMA(a2[i], b2[j], ctx[i][j]);
    }
  }
  float* base = ctx4 + (long)(nc * 96 + bh) * (MFEAT * DHEAD);
#pragma unroll
  for (int i = 0; i < 4; ++i)
#pragma unroll
    for (int j = 0; j < 4; ++j)
#pragma unroll
      for (int r = 0; r < 4; ++r)
        base[(long)(wc + i * 16 + lk * 4 + r) * DHEAD + j * 16 + l15] = ctx[i][j][r];
#pragma unroll
  for (int j = 0; j < 4; ++j) {
    float s = cs[j];
    s += __shfl_xor(s, 16);
    s += __shfl_xor(s, 32);
    if (lk == 0)
      kpart[((long)bh * 4 + nc) * MFEAT + wc + j * 16 + l15] = s;
  }
}

// ---------------- K3b: Baug[bh][80][256] = [context^T ; k_sum ; 0] ----------------
__global__ void k3b(const float* __restrict__ ctx4, const float* __restrict__ kpart,
                    u16* __restrict__ baug) {
  int bh = blockIdx.x, m = threadIdx.x;
  u16* o = baug + (long)bh * 80 * MFEAT;
#pragma unroll 4
  for (int dd = 0; dd < 64; ++dd) {
    float s = 0.f;
    for (int c = 0; c < 4; ++c) s += ctx4[(long)(c * 96 + bh) * (MFEAT * DHEAD) + m * DHEAD + dd];
    o[dd * MFEAT + m] = f2bf(s);
  }
  float ks = 0.f;
  for (int c = 0; c < 4; ++c) ks += kpart[((long)bh * 4 + c) * MFEAT + m];
  o[64 * MFEAT + m] = f2bf(ks);
  for (int dd = 65; dd < 80; ++dd) o[dd * MFEAT + m] = 0;
}

// ---------------- K5: attn = (q' @ Baug^T) * inv-denominator (one quarter) ----------------
__global__ __launch_bounds__(256) void k5_out(const u16* __restrict__ qpQ, const u16* __restrict__ baug,
                                              u16* __restrict__ attnQ) {
  __shared__ u16 st[4 * 64 * 72];
  int bh = blockIdx.y;
  int b = bh / H_, h = bh % H_;
  int tid = threadIdx.x, lane = tid & 63, wid = tid >> 6;
  int l15 = lane & 15, lk = lane >> 4;
  int rbase = blockIdx.x * 256 + wid * 64;  // local within quarter
  const u16* Aq = qpQ + ((long)bh * 1024 + rbase) * MFEAT;
  const u16* Bb = baug + (long)bh * 80 * MFEAT;
  f32x4 acc[4][5];
#pragma unroll
  for (int i = 0; i < 4; ++i)
#pragma unroll
    for (int j = 0; j < 5; ++j) acc[i][j] = (f32x4){0.f, 0.f, 0.f, 0.f};
#pragma unroll 2
  for (int ks = 0; ks < 8; ++ks) {
    s16x8 a[4], bv[5];
#pragma unroll
    for (int i = 0; i < 4; ++i)
      a[i] = *(const s16x8*)(Aq + (long)(i * 16 + l15) * MFEAT + ks * 32 + lk * 8);
#pragma unroll
    for (int j = 0; j < 5; ++j)
      bv[j] = *(const s16x8*)(Bb + (long)(j * 16 + l15) * MFEAT + ks * 32 + lk * 8);
#pragma unroll
    for (int i = 0; i < 4; ++i)
#pragma unroll
      for (int j = 0; j < 5; ++j) acc[i][j] = MFMA(a[i], bv[j], acc[i][j]);
  }
  u16* stw = st + wid * 64 * 72;
#pragma unroll
  for (int i = 0; i < 4; ++i)
#pragma unroll
    for (int r = 0; r < 4; ++r) {
      float dn = __shfl(acc[i][4][r], lane & 48, 64);  // col 64 = denom, lives in l15==0
      float inv = 1.0f / dn;
      int row = i * 16 + lk * 4 + r;
#pragma unroll
      for (int j = 0; j < 4; ++j)
        stw[row * 72 + j * 16 + l15] = f2bf(acc[i][j][r] * inv);
    }
  u16* dst = attnQ + ((long)b * 1024 + rbase) * CDIM + h * DHEAD;
  st_write64(stw, dst, CDIM, lane);
}

// ---------------- K6: out = attn @ w_proj^T + b_proj (one quarter, fp32 out) ----------------
__global__ __launch_bounds__(256) void k6_proj(const u16* __restrict__ A, const u16* __restrict__ Bm,
                                               const float* __restrict__ bproj, float* __restrict__ out,
                                               int qtr) {
  __shared__ u16 lA[128 * 40];
  __shared__ u16 lB[128 * 40];
  int tid = threadIdx.x, lane = tid & 63, wid = tid >> 6;
  int wr = (wid >> 1) << 6, wc = (wid & 1) << 6;
  int srow = tid >> 2, sch = tid & 3;
  int l15 = lane & 15, lk = lane >> 4;
  int m0 = blockIdx.x << 7, n0 = blockIdx.y << 7;  // m0 in [0,8192)
  const u16* Ab = A + (long)m0 * CDIM;
  const u16* Bb = Bm + (long)n0 * CDIM;
  f32x4 acc[4][4];
#pragma unroll
  for (int i = 0; i < 4; ++i)
#pragma unroll
    for (int j = 0; j < 4; ++j) acc[i][j] = (f32x4){0.f, 0.f, 0.f, 0.f};
  for (int k0 = 0; k0 < CDIM; k0 += 32) {
    __syncthreads();
    *(s16x8*)(lA + srow * 40 + sch * 8) = *(const s16x8*)(Ab + (long)srow * CDIM + k0 + sch * 8);
    *(s16x8*)(lA + (srow + 64) * 40 + sch * 8) = *(const s16x8*)(Ab + (long)(srow + 64) * CDIM + k0 + sch * 8);
    *(s16x8*)(lB + srow * 40 + sch * 8) = *(const s16x8*)(Bb + (long)srow * CDIM + k0 + sch * 8);
    *(s16x8*)(lB + (srow + 64) * 40 + sch * 8) = *(const s16x8*)(Bb + (long)(srow + 64) * CDIM + k0 + sch * 8);
    __syncthreads();
    s16x8 af[4], bv[4];
#pragma unroll
    for (int i = 0; i < 4; ++i) {
      af[i] = *(const s16x8*)(lA + (wr + i * 16 + l15) * 40 + lk * 8);
      bv[i] = *(const s16x8*)(lB + (wc + i * 16 + l15) * 40 + lk * 8);
    }
#pragma unroll
    for (int i = 0; i < 4; ++i)
#pragma unroll
      for (int j = 0; j < 4; ++j) acc[i][j] = MFMA(af[i], bv[j], acc[i][j]);
  }
  float bpv[4];
#pragma unroll
  for (int j = 0; j < 4; ++j) bpv[j] = bproj[n0 + wc + j * 16 + l15];
  // map local quarter rows -> global out rows: b = m0>>10, t = m0&1023
  long growbase = (long)(m0 >> 10) * NTOK + (long)qtr * 1024 + (m0 & 1023);
#pragma unroll
  for (int i = 0; i < 4; ++i)
#pragma unroll
    for (int j = 0; j < 4; ++j)
#pragma unroll
      for (int r = 0; r < 4; ++r) {
        long row = growbase + wr + i * 16 + lk * 4 + r;
        int col = n0 + wc + j * 16 + l15;
        out[row * CDIM + col] = acc[i][j][r] + bpv[j];
      }
}

extern "C" void kernel_launch(void* const* d_in, const int* in_sizes, int n_in,
                              void* d_out, int out_size, void* d_ws, size_t ws_size,
                              hipStream_t stream) {
  const float* x = (const float*)d_in[0];
  const float* w_qkv = (const float*)d_in[1];
  const float* w_proj = (const float*)d_in[2];
  const float* b_proj = (const float*)d_in[3];
  const float* proj = (const float*)d_in[4];
  float* out = (float*)d_out;

  char* p = (char*)d_ws;
  auto take = [&](size_t bytes) {
    char* r = p;
    p += (bytes + 255) & ~(size_t)255;
    return r;
  };
  // region A: xb -> (dead after k0) -> ctx4 -> (dead after k3b) -> attnQ
  u16* xb = (u16*)take(32768UL * 768 * 2);        // 50.33 MB
  u16* wqkvb = (u16*)take(2304UL * 768 * 2);
  u16* wprojb = (u16*)take(768UL * 768 * 2);
  u16* projb = (u16*)take(256UL * 64 * 2);
  u16* qb = (u16*)take(96UL * 4096 * 64 * 2);     // 50.33 MB
  // region B: kb -> (dead after k3f) -> qpQ (exact same size)
  u16* kb = (u16*)take(96UL * 4096 * 64 * 2);     // 50.33 MB
  u16* vT = (u16*)take(96UL * 64 * 4096 * 2);     // 50.33 MB
  float* kpart = (float*)take(96UL * 4 * 256 * 4);
  u32* mk = (u32*)take(256);
  u16* baug = (u16*)take(96UL * 80 * 256 * 2);
  // aliases (stream-ordered, no lifetime overlap)
  float* ctx4 = (float*)xb;   // 25.17 MB <= 50.33 MB
  u16* attnQ = xb;            // 12.58 MB <= 50.33 MB
  u16* qpQ = kb;              // 50.33 MB == 50.33 MB

  k_init<<<1, 64, 0, stream>>>(mk);
  cvt_bf16<<<(25165824 / 4 + 255) / 256, 256, 0, stream>>>(x, xb, 25165824 / 4);
  cvt_bf16<<<(1769472 / 4 + 255) / 256, 256, 0, stream>>>(w_qkv, wqkvb, 1769472 / 4);
  cvt_bf16<<<(589824 / 4 + 255) / 256, 256, 0, stream>>>(w_proj, wprojb, 589824 / 4);
  cvt_bf16<<<(16384 / 4 + 255) / 256, 256, 0, stream>>>(proj, projb, 16384 / 4);
  k0_qkv<<<dim3(256, 18), 256, 0, stream>>>(xb, wqkvb, qb, kb, vT);
  k2_k1<<<dim3(64, 96), 256, 0, stream>>>(kb, projb, mk);
  k3f<<<dim3(4, 96), 256, 0, stream>>>(kb, vT, projb, mk, ctx4, kpart);
  k3b<<<96, 256, 0, stream>>>(ctx4, kpart, baug);
  for (int qtr = 0; qtr < 4; ++qtr) {
    k2_q<<<dim3(16, 96), 256, 0, stream>>>(qb, projb, qpQ, qtr);
    k5_out<<<dim3(4, 96), 256, 0, stream>>>(qpQ, baug, attnQ);
    k6_proj<<<dim3(64, 6), 256, 0, stream>>>(attnQ, wprojb, b_proj, out, qtr);
  }
}

// Round 4
// 699.160 us; speedup vs baseline: 1.0823x; 1.0823x over previous
//
#include <hip/hip_runtime.h>
#include <hip/hip_bf16.h>

typedef __attribute__((ext_vector_type(4))) float f32x4;
typedef __attribute__((ext_vector_type(8))) short s16x8;
typedef __attribute__((ext_vector_type(4))) float f4v;
typedef __attribute__((ext_vector_type(4))) unsigned short us4;
typedef unsigned short u16;
typedef unsigned int u32;

#define H_ 12
#define NTOK 4096
#define DHEAD 64
#define MFEAT 256
#define CDIM 768

#define NORMALIZER 0.35355339059327373f  /* 64^-0.25 */
#define DIAGSCALE 0.0625f                /* 0.5 * NORMALIZER^2 */
#define RATIO_ 0.0625f                   /* 256^-0.5 */
#define EPS_ 1e-4f

#define MFMA(a, b, c) __builtin_amdgcn_mfma_f32_16x16x32_bf16((a), (b), (c), 0, 0, 0)

__device__ __forceinline__ float bf2f(u16 u) {
  union { float f; u32 v; } x; x.v = ((u32)u) << 16; return x.f;
}
__device__ __forceinline__ u16 f2bf(float f) {
  union { float f; u32 v; } x; x.f = f;
  u32 v = x.v + 0x7FFFu + ((x.v >> 16) & 1u);
  return (u16)(v >> 16);
}
__device__ __forceinline__ u32 fenc(float f) {
  u32 u = __float_as_uint(f);
  return (u & 0x80000000u) ? ~u : (u | 0x80000000u);
}
__device__ __forceinline__ float fdec(u32 k) {
  u32 u = (k & 0x80000000u) ? (k & 0x7fffffffu) : ~k;
  return __uint_as_float(u);
}
__device__ __forceinline__ void glds16(const u16* g, u16* l) {
  __builtin_amdgcn_global_load_lds((const __attribute__((address_space(1))) void*)g,
                                   (__attribute__((address_space(3))) void*)l, 16, 0, 0);
}

// write a wave's staged 64x64 bf16 tile (rows padded to 72) to dst
__device__ __forceinline__ void st_write64(const u16* stw, u16* dst, long ld, int lane) {
  int r0 = lane >> 3, cc = lane & 7;
#pragma unroll
  for (int c = 0; c < 8; ++c) {
    int row = c * 8 + r0;
    s16x8 v = *(const s16x8*)(stw + row * 72 + cc * 8);
    *(s16x8*)(dst + (long)row * ld + cc * 8) = v;
  }
}

__global__ void k_init(u32* mk) {
  if (threadIdx.x < 8) mk[threadIdx.x] = 0u;
}

__global__ void cvt_bf16(const float* __restrict__ in, u16* __restrict__ out, int n4) {
  int i = blockIdx.x * 256 + threadIdx.x;
  if (i >= n4) return;
  f4v v = *(const f4v*)(in + (long)i * 4);
  us4 o;
#pragma unroll
  for (int j = 0; j < 4; ++j) o[j] = f2bf(v[j]);
  *(us4*)(out + (long)i * 4) = o;
}

// ---------------- K0: QKV GEMM, m97-structure (global_load_lds + src-swizzle) ----------------
__global__ __launch_bounds__(256) void k0_qkv(const u16* __restrict__ A, const u16* __restrict__ Bm,
                                              u16* __restrict__ qb, u16* __restrict__ kb,
                                              u16* __restrict__ vT) {
  __shared__ u16 smem[4 * 64 * 72];   // loop: lA[0,4096) lB[4096,8192); epilogue: 4x 64x72
  u16* lA = smem;
  u16* lB = smem + 4096;
  int tid = threadIdx.x, lane = tid & 63, wid = tid >> 6;
  // XCD swizzle (nwg = 4608, %8 == 0)
  int lid = blockIdx.x + (blockIdx.y << 8);
  int swz = (lid & 7) * 576 + (lid >> 3);
  int bx = swz & 255, by = swz >> 8;
  int m0 = bx << 7, n0 = by << 7;
  int wr = (wid >> 1) << 6, wc = (wid & 1) << 6;
  int l15 = lane & 15, lk = lane >> 4;
  int u8 = (lk ^ ((l15 >> 2) & 3)) * 8;  // swizzled 16B unit for frag reads
  int pr = lane >> 2;
  int c0 = (((lane & 3) ^ ((pr >> 2) & 3))) * 8;  // pre-swizzled source col (u16)
  int rr0 = wid * 32 + pr, rr1 = rr0 + 16;
  const u16* Ab = A + (long)m0 * CDIM;
  const u16* Bb = Bm + (long)n0 * CDIM;
  const u16* ga0 = Ab + (long)rr0 * CDIM + c0;
  const u16* ga1 = Ab + (long)rr1 * CDIM + c0;
  const u16* gb0 = Bb + (long)rr0 * CDIM + c0;
  const u16* gb1 = Bb + (long)rr1 * CDIM + c0;
  u16* dA0 = lA + (wid * 2) * 512;
  u16* dA1 = lA + (wid * 2 + 1) * 512;
  u16* dB0 = lB + (wid * 2) * 512;
  u16* dB1 = lB + (wid * 2 + 1) * 512;
  f32x4 acc[4][4];
#pragma unroll
  for (int i = 0; i < 4; ++i)
#pragma unroll
    for (int j = 0; j < 4; ++j) acc[i][j] = (f32x4){0.f, 0.f, 0.f, 0.f};
  for (int k0 = 0; k0 < CDIM; k0 += 32) {
    __syncthreads();
    glds16(ga0 + k0, dA0);
    glds16(ga1 + k0, dA1);
    glds16(gb0 + k0, dB0);
    glds16(gb1 + k0, dB1);
    __syncthreads();
    s16x8 af[4], bv[4];
#pragma unroll
    for (int i = 0; i < 4; ++i) {
      af[i] = *(const s16x8*)(lA + (wr + i * 16 + l15) * 32 + u8);
      bv[i] = *(const s16x8*)(lB + (wc + i * 16 + l15) * 32 + u8);
    }
#pragma unroll
    for (int i = 0; i < 4; ++i)
#pragma unroll
      for (int j = 0; j < 4; ++j) acc[i][j] = MFMA(af[i], bv[j], acc[i][j]);
  }
  __syncthreads();  // before reusing smem as epilogue stage
  int colbase = n0 + wc;
  int qi = colbase / CDIM;
  int h = (colbase % CDIM) >> 6;
  int rowbase = m0 + wr;
  int b = rowbase >> 12;
  int nloc = rowbase & (NTOK - 1);
  u16* stw = smem + wid * 4608;
  if (qi < 2) {
#pragma unroll
    for (int i = 0; i < 4; ++i)
#pragma unroll
      for (int j = 0; j < 4; ++j)
#pragma unroll
        for (int r = 0; r < 4; ++r)
          stw[(i * 16 + lk * 4 + r) * 72 + j * 16 + l15] = f2bf(acc[i][j][r]);
    u16* dst = (qi == 0 ? qb : kb) + ((long)(b * H_ + h) * NTOK + nloc) * DHEAD;
    st_write64(stw, dst, DHEAD, lane);
  } else {
    // transposed stage: st[dd][n] (pack 4 r's into one b64)
#pragma unroll
    for (int i = 0; i < 4; ++i)
#pragma unroll
      for (int j = 0; j < 4; ++j) {
        us4 w;
#pragma unroll
        for (int r = 0; r < 4; ++r) w[r] = f2bf(acc[i][j][r]);
        *(us4*)(stw + (j * 16 + l15) * 72 + i * 16 + lk * 4) = w;
      }
    u16* dst = vT + (long)(b * H_ + h) * DHEAD * NTOK + nloc;
    st_write64(stw, dst, NTOK, lane);
  }
}

// ---------------- K2k pass1: global max of k_dash per batch ----------------
__global__ __launch_bounds__(256) void k2_k1(const u16* __restrict__ kb, const u16* __restrict__ projb,
                                             u32* __restrict__ mk) {
  __shared__ float wmax[4];
  int bh = blockIdx.y;
  int n0 = blockIdx.x << 6;
  const u16* Aq = kb + ((long)bh * NTOK + n0) * DHEAD;
  int tid = threadIdx.x, lane = tid & 63, wid = tid >> 6;
  int wc = wid << 6;
  int l15 = lane & 15, lk = lane >> 4;
  f32x4 acc[4][4];
#pragma unroll
  for (int i = 0; i < 4; ++i)
#pragma unroll
    for (int j = 0; j < 4; ++j) acc[i][j] = (f32x4){0.f, 0.f, 0.f, 0.f};
#pragma unroll
  for (int ks = 0; ks < 2; ++ks) {
    s16x8 a[4], bv[4];
#pragma unroll
    for (int i = 0; i < 4; ++i)
      a[i] = *(const s16x8*)(Aq + (long)(i * 16 + l15) * DHEAD + ks * 32 + lk * 8);
#pragma unroll
    for (int j = 0; j < 4; ++j)
      bv[j] = *(const s16x8*)(projb + (long)(wc + j * 16 + l15) * DHEAD + ks * 32 + lk * 8);
#pragma unroll
    for (int i = 0; i < 4; ++i)
#pragma unroll
      for (int j = 0; j < 4; ++j) acc[i][j] = MFMA(a[i], bv[j], acc[i][j]);
  }
  float m = -3.4e38f;
#pragma unroll
  for (int i = 0; i < 4; ++i)
#pragma unroll
    for (int j = 0; j < 4; ++j)
#pragma unroll
      for (int r = 0; r < 4; ++r) m = fmaxf(m, acc[i][j][r]);
  m = fmaxf(m, __shfl_xor(m, 1));
  m = fmaxf(m, __shfl_xor(m, 2));
  m = fmaxf(m, __shfl_xor(m, 4));
  m = fmaxf(m, __shfl_xor(m, 8));
  m = fmaxf(m, __shfl_xor(m, 16));
  m = fmaxf(m, __shfl_xor(m, 32));
  if (lane == 0) wmax[wid] = m;
  __syncthreads();
  if (tid == 0) {
    float mm = fmaxf(fmaxf(wmax[0], wmax[1]), fmaxf(wmax[2], wmax[3])) * NORMALIZER;
    atomicMax(mk + (blockIdx.y / H_), fenc(mm));
  }
}

// ---------------- K3f: fused phi(k) + context = k'^T @ v (512-token chunk, barrier-free) ----------------
__global__ __launch_bounds__(256) void k3f(const u16* __restrict__ kb, const u16* __restrict__ vT,
                                           const u16* __restrict__ projb, const u32* __restrict__ mk,
                                           float* __restrict__ ctx8, float* __restrict__ kpart) {
  __shared__ u16 smem[4 * 64 * 72];
  int bh = blockIdx.y, nc = blockIdx.x;  // nc in [0,8)
  int tid = threadIdx.x, lane = tid & 63, wid = tid >> 6;
  int l15 = lane & 15, lk = lane >> 4;
  int wc = wid << 6;
  float mg = fdec(mk[bh / H_]);
  const u16* Kb = kb + ((long)bh * NTOK + nc * 512) * DHEAD;
  const u16* Vb = vT + (long)bh * DHEAD * NTOK + nc * 512;
  u16* ktw = smem + wid * 4608;  // per-wave [64 feat][72] tile (wave-local!)
  f32x4 ctxa[4][4];
#pragma unroll
  for (int i = 0; i < 4; ++i)
#pragma unroll
    for (int j = 0; j < 4; ++j) ctxa[i][j] = (f32x4){0.f, 0.f, 0.f, 0.f};
  float cs[4] = {0.f, 0.f, 0.f, 0.f};
  for (int sb = 0; sb < 8; ++sb) {
    const u16* Ksb = Kb + sb * 64 * DHEAD;
    s16x8 a[4][2];
    float ss[4] = {0.f, 0.f, 0.f, 0.f};
#pragma unroll
    for (int i = 0; i < 4; ++i)
#pragma unroll
      for (int ks = 0; ks < 2; ++ks) {
        a[i][ks] = *(const s16x8*)(Ksb + (long)(i * 16 + l15) * DHEAD + ks * 32 + lk * 8);
#pragma unroll
        for (int e = 0; e < 8; ++e) { float f = bf2f((u16)a[i][ks][e]); ss[i] += f * f; }
      }
    float dgv[4];
#pragma unroll
    for (int i = 0; i < 4; ++i) {
      float s = ss[i];
      s += __shfl_xor(s, 16);
      s += __shfl_xor(s, 32);
      dgv[i] = s * DIAGSCALE;  // diag of token 16i+l15 (uniform over lk)
    }
    f32x4 dacc[4][4];
#pragma unroll
    for (int i = 0; i < 4; ++i)
#pragma unroll
      for (int j = 0; j < 4; ++j) dacc[i][j] = (f32x4){0.f, 0.f, 0.f, 0.f};
#pragma unroll
    for (int ks = 0; ks < 2; ++ks)
#pragma unroll
      for (int j = 0; j < 4; ++j) {
        s16x8 pb = *(const s16x8*)(projb + (long)(wc + j * 16 + l15) * DHEAD + ks * 32 + lk * 8);
#pragma unroll
        for (int i = 0; i < 4; ++i) dacc[i][j] = MFMA(a[i][ks], pb, dacc[i][j]);
      }
    // diag at token 16i+4lk+r via shuffle
    float dgr[4][4];
#pragma unroll
    for (int i = 0; i < 4; ++i)
#pragma unroll
      for (int r = 0; r < 4; ++r) dgr[i][r] = __shfl(dgv[i], 4 * lk + r);
    // phi -> kT (wave-local), packed b64 writes
#pragma unroll
    for (int i = 0; i < 4; ++i)
#pragma unroll
      for (int j = 0; j < 4; ++j) {
        us4 w;
#pragma unroll
        for (int r = 0; r < 4; ++r) {
          float v = RATIO_ * (__expf(dacc[i][j][r] * NORMALIZER - dgr[i][r] - mg) + EPS_);
          cs[j] += v;
          w[r] = f2bf(v);
        }
        *(us4*)(ktw + (j * 16 + l15) * 72 + i * 16 + lk * 4) = w;
      }
    // context MFMA: A = k'(features) rows from ktw, B = vT rows
#pragma unroll
    for (int ks = 0; ks < 2; ++ks) {
      s16x8 a2f[4], vb[4];
#pragma unroll
      for (int ii = 0; ii < 4; ++ii)
        a2f[ii] = *(const s16x8*)(ktw + (ii * 16 + l15) * 72 + ks * 32 + lk * 8);
#pragma unroll
      for (int jv = 0; jv < 4; ++jv)
        vb[jv] = *(const s16x8*)(Vb + (long)(jv * 16 + l15) * NTOK + sb * 64 + ks * 32 + lk * 8);
#pragma unroll
      for (int ii = 0; ii < 4; ++ii)
#pragma unroll
        for (int jv = 0; jv < 4; ++jv) ctxa[ii][jv] = MFMA(a2f[ii], vb[jv], ctxa[ii][jv]);
    }
  }
  float* base = ctx8 + (long)(nc * 96 + bh) * (MFEAT * DHEAD);
#pragma unroll
  for (int ii = 0; ii < 4; ++ii)
#pragma unroll
    for (int jv = 0; jv < 4; ++jv)
#pragma unroll
      for (int r = 0; r < 4; ++r)
        base[(long)(wc + ii * 16 + lk * 4 + r) * DHEAD + jv * 16 + l15] = ctxa[ii][jv][r];
#pragma unroll
  for (int j = 0; j < 4; ++j) {
    float s = cs[j];
    s += __shfl_xor(s, 16);
    s += __shfl_xor(s, 32);
    if (lk == 0) kpart[((long)bh * 8 + nc) * MFEAT + wc + j * 16 + l15] = s;
  }
}

// ---------------- K3b: Baug[bh][80][256] = [ctx^T ; k_sum ; 0] + f32 row-sums bsum[bh][80] ----------------
__global__ __launch_bounds__(256) void k3b(const float* __restrict__ ctx8, const float* __restrict__ kpart,
                                           u16* __restrict__ baug, float* __restrict__ bsum) {
  __shared__ float red[4];
  int bh = blockIdx.x, m = threadIdx.x;
  int lane = m & 63, wid = m >> 6;
  u16* o = baug + (long)bh * 80 * MFEAT;
  for (int dd = 0; dd < 64; ++dd) {
    float s = 0.f;
    for (int c = 0; c < 8; ++c) s += ctx8[(long)(c * 96 + bh) * (MFEAT * DHEAD) + m * DHEAD + dd];
    o[dd * MFEAT + m] = f2bf(s);
    float t = s;
    t += __shfl_xor(t, 1); t += __shfl_xor(t, 2); t += __shfl_xor(t, 4);
    t += __shfl_xor(t, 8); t += __shfl_xor(t, 16); t += __shfl_xor(t, 32);
    if (lane == 0) red[wid] = t;
    __syncthreads();
    if (m == 0) bsum[bh * 80 + dd] = red[0] + red[1] + red[2] + red[3];
    __syncthreads();
  }
  float ks = 0.f;
  for (int c = 0; c < 8; ++c) ks += kpart[((long)bh * 8 + c) * MFEAT + m];
  o[64 * MFEAT + m] = f2bf(ks);
  float t = ks;
  t += __shfl_xor(t, 1); t += __shfl_xor(t, 2); t += __shfl_xor(t, 4);
  t += __shfl_xor(t, 8); t += __shfl_xor(t, 16); t += __shfl_xor(t, 32);
  if (lane == 0) red[wid] = t;
  __syncthreads();
  if (m == 0) bsum[bh * 80 + 64] = red[0] + red[1] + red[2] + red[3];
  for (int dd = 65; dd < 80; ++dd) o[dd * MFEAT + m] = 0;
  if (m < 15) bsum[bh * 80 + 65 + m] = 0.f;
}

// ---------------- K2Q5: fused phi(q) + (q' @ Baug^T), online max, analytic eps ----------------
__global__ __launch_bounds__(256) void k2q5(const u16* __restrict__ qb, const u16* __restrict__ projb,
                                            const u16* __restrict__ baug, const float* __restrict__ bsum,
                                            u16* __restrict__ attn) {
  __shared__ u16 smem[4 * 64 * 72];
  int bh = blockIdx.y;
  int b = bh / H_, h = bh % H_;
  int tid = threadIdx.x, lane = tid & 63, wid = tid >> 6;
  int l15 = lane & 15, lk = lane >> 4;
  int tb = blockIdx.x * 256 + wid * 64;  // wave's 64 tokens
  const u16* Aq = qb + ((long)bh * NTOK + tb) * DHEAD;
  const u16* Bb = baug + (long)bh * 80 * MFEAT;
  u16* qTw = smem + wid * 4608;  // loop: [64 tok][40]; epilogue: [64][72]

  // resident q fragments + diag (token = 16i+l15)
  s16x8 a2[4][2];
  float ssv[4] = {0.f, 0.f, 0.f, 0.f};
#pragma unroll
  for (int i = 0; i < 4; ++i)
#pragma unroll
    for (int ks = 0; ks < 2; ++ks) {
      a2[i][ks] = *(const s16x8*)(Aq + (long)(i * 16 + l15) * DHEAD + ks * 32 + lk * 8);
#pragma unroll
      for (int e = 0; e < 8; ++e) { float f = bf2f((u16)a2[i][ks][e]); ssv[i] += f * f; }
    }
  float dgv[4];
#pragma unroll
  for (int i = 0; i < 4; ++i) {
    float s = ssv[i];
    s += __shfl_xor(s, 16);
    s += __shfl_xor(s, 32);
    dgv[i] = s * DIAGSCALE;
  }
  float rm[4] = {-3.4e38f, -3.4e38f, -3.4e38f, -3.4e38f};
  f32x4 oacc[5][4];  // [baug-frag jo][token-frag i]; row=16jo+4lk+r, col(token)=16i+l15
#pragma unroll
  for (int jo = 0; jo < 5; ++jo)
#pragma unroll
    for (int i = 0; i < 4; ++i) oacc[jo][i] = (f32x4){0.f, 0.f, 0.f, 0.f};

  for (int c = 0; c < 8; ++c) {  // 32-feature chunks
    // swapped dash: mfma(proj, q) -> row=feature(16j+4lk+r), col=token(16i+l15)
    s16x8 pb[2][2];
#pragma unroll
    for (int j = 0; j < 2; ++j)
#pragma unroll
      for (int ks = 0; ks < 2; ++ks)
        pb[j][ks] = *(const s16x8*)(projb + (long)(c * 32 + j * 16 + l15) * DHEAD + ks * 32 + lk * 8);
    f32x4 dacc[2][4];
#pragma unroll
    for (int j = 0; j < 2; ++j)
#pragma unroll
      for (int i = 0; i < 4; ++i) dacc[j][i] = (f32x4){0.f, 0.f, 0.f, 0.f};
#pragma unroll
    for (int ks = 0; ks < 2; ++ks)
#pragma unroll
      for (int j = 0; j < 2; ++j)
#pragma unroll
        for (int i = 0; i < 4; ++i) dacc[j][i] = MFMA(pb[j][ks], a2[i][ks], dacc[j][i]);
    // online max per token (in-lane over 8 feats, then 2 shfl over lk)
    float fsc[4];
#pragma unroll
    for (int i = 0; i < 4; ++i) {
      float cm = dacc[0][i][0];
      cm = fmaxf(cm, dacc[0][i][1]); cm = fmaxf(cm, dacc[0][i][2]); cm = fmaxf(cm, dacc[0][i][3]);
      cm = fmaxf(cm, dacc[1][i][0]); cm = fmaxf(cm, dacc[1][i][1]);
      cm = fmaxf(cm, dacc[1][i][2]); cm = fmaxf(cm, dacc[1][i][3]);
      cm = fmaxf(cm, __shfl_xor(cm, 16));
      cm = fmaxf(cm, __shfl_xor(cm, 32));
      float rn = fmaxf(rm[i], cm);
      fsc[i] = __expf((rm[i] - rn) * NORMALIZER);
      rm[i] = rn;
    }
#pragma unroll
    for (int jo = 0; jo < 5; ++jo)
#pragma unroll
      for (int i = 0; i < 4; ++i) oacc[jo][i] *= fsc[i];
    // phi (NO eps -- handled analytically) -> wave-local LDS [64 tok][40], packed b64
#pragma unroll
    for (int i = 0; i < 4; ++i) {
      float dm = dgv[i] + rm[i] * NORMALIZER;
#pragma unroll
      for (int j = 0; j < 2; ++j) {
        us4 w;
#pragma unroll
        for (int r = 0; r < 4; ++r)
          w[r] = f2bf(RATIO_ * __expf(dacc[j][i][r] * NORMALIZER - dm));
        *(us4*)(qTw + (i * 16 + l15) * 40 + j * 16 + lk * 4) = w;
      }
    }
    // out MFMA: A = Baug rows, B = q' tokens (read back from LDS)
    s16x8 bB[5], qf[4];
#pragma unroll
    for (int jo = 0; jo < 5; ++jo)
      bB[jo] = *(const s16x8*)(Bb + (long)(jo * 16 + l15) * MFEAT + c * 32 + lk * 8);
#pragma unroll
    for (int i = 0; i < 4; ++i)
      qf[i] = *(const s16x8*)(qTw + (i * 16 + l15) * 40 + lk * 8);
#pragma unroll
    for (int jo = 0; jo < 5; ++jo)
#pragma unroll
      for (int i = 0; i < 4; ++i) oacc[jo][i] = MFMA(bB[jo], qf[i], oacc[jo][i]);
  }
  // analytic eps term: out += ratio*eps*rowsum(Baug[br]) (exact, unaffected by rescale)
#pragma unroll
  for (int jo = 0; jo < 5; ++jo) {
    f4v bs = *(const f4v*)(bsum + (long)bh * 80 + jo * 16 + lk * 4);
#pragma unroll
    for (int i = 0; i < 4; ++i)
#pragma unroll
      for (int r = 0; r < 4; ++r) oacc[jo][i][r] += (RATIO_ * EPS_) * bs[r];
  }
  // epilogue: divide by denominator (baug row 64 -> lanes lk==0, r==0), stage, write
  u16* stw = qTw;  // stride 72 now
#pragma unroll
  for (int i = 0; i < 4; ++i) {
    float dn = __shfl(oacc[4][i][0], l15);  // token 16i+l15's denom from lane (l15, lk=0)
    float inv = 1.0f / dn;
#pragma unroll
    for (int jo = 0; jo < 4; ++jo) {
      us4 w;
#pragma unroll
      for (int r = 0; r < 4; ++r) w[r] = f2bf(oacc[jo][i][r] * inv);
      *(us4*)(stw + (i * 16 + l15) * 72 + jo * 16 + lk * 4) = w;
    }
  }
  u16* dst = attn + ((long)b * NTOK + tb) * CDIM + h * DHEAD;
  st_write64(stw, dst, CDIM, lane);
}

// ---------------- K6: out = attn @ w_proj^T + b_proj (m97-structure, fp32 out) ----------------
__global__ __launch_bounds__(256) void k6_proj(const u16* __restrict__ A, const u16* __restrict__ Bm,
                                               const float* __restrict__ bproj, float* __restrict__ out) {
  __shared__ u16 smem[8192];
  u16* lA = smem;
  u16* lB = smem + 4096;
  int tid = threadIdx.x, lane = tid & 63, wid = tid >> 6;
  int lid = blockIdx.x + (blockIdx.y << 8);   // nwg = 1536, %8 == 0
  int swz = (lid & 7) * 192 + (lid >> 3);
  int bx = swz & 255, by = swz >> 8;
  int m0 = bx << 7, n0 = by << 7;
  int wr = (wid >> 1) << 6, wc = (wid & 1) << 6;
  int l15 = lane & 15, lk = lane >> 4;
  int u8 = (lk ^ ((l15 >> 2) & 3)) * 8;
  int pr = lane >> 2;
  int c0 = (((lane & 3) ^ ((pr >> 2) & 3))) * 8;
  int rr0 = wid * 32 + pr, rr1 = rr0 + 16;
  const u16* Ab = A + (long)m0 * CDIM;
  const u16* Bb = Bm + (long)n0 * CDIM;
  const u16* ga0 = Ab + (long)rr0 * CDIM + c0;
  const u16* ga1 = Ab + (long)rr1 * CDIM + c0;
  const u16* gb0 = Bb + (long)rr0 * CDIM + c0;
  const u16* gb1 = Bb + (long)rr1 * CDIM + c0;
  u16* dA0 = lA + (wid * 2) * 512;
  u16* dA1 = lA + (wid * 2 + 1) * 512;
  u16* dB0 = lB + (wid * 2) * 512;
  u16* dB1 = lB + (wid * 2 + 1) * 512;
  f32x4 acc[4][4];
#pragma unroll
  for (int i = 0; i < 4; ++i)
#pragma unroll
    for (int j = 0; j < 4; ++j) acc[i][j] = (f32x4){0.f, 0.f, 0.f, 0.f};
  for (int k0 = 0; k0 < CDIM; k0 += 32) {
    __syncthreads();
    glds16(ga0 + k0, dA0);
    glds16(ga1 + k0, dA1);
    glds16(gb0 + k0, dB0);
    glds16(gb1 + k0, dB1);
    __syncthreads();
    s16x8 af[4], bv[4];
#pragma unroll
    for (int i = 0; i < 4; ++i) {
      af[i] = *(const s16x8*)(lA + (wr + i * 16 + l15) * 32 + u8);
      bv[i] = *(const s16x8*)(lB + (wc + i * 16 + l15) * 32 + u8);
    }
#pragma unroll
    for (int i = 0; i < 4; ++i)
#pragma unroll
      for (int j = 0; j < 4; ++j) acc[i][j] = MFMA(af[i], bv[j], acc[i][j]);
  }
  float bpv[4];
#pragma unroll
  for (int j = 0; j < 4; ++j) bpv[j] = bproj[n0 + wc + j * 16 + l15];
#pragma unroll
  for (int i = 0; i < 4; ++i)
#pragma unroll
    for (int j = 0; j < 4; ++j)
#pragma unroll
      for (int r = 0; r < 4; ++r) {
        long row = m0 + wr + i * 16 + lk * 4 + r;
        int col = n0 + wc + j * 16 + l15;
        out[row * CDIM + col] = acc[i][j][r] + bpv[j];
      }
}

extern "C" void kernel_launch(void* const* d_in, const int* in_sizes, int n_in,
                              void* d_out, int out_size, void* d_ws, size_t ws_size,
                              hipStream_t stream) {
  const float* x = (const float*)d_in[0];
  const float* w_qkv = (const float*)d_in[1];
  const float* w_proj = (const float*)d_in[2];
  const float* b_proj = (const float*)d_in[3];
  const float* proj = (const float*)d_in[4];
  float* out = (float*)d_out;

  char* p = (char*)d_ws;
  auto take = [&](size_t bytes) {
    char* r = p;
    p += (bytes + 255) & ~(size_t)255;
    return r;
  };
  u16* xb = (u16*)take(32768UL * 768 * 2);      // 50.33 MB; dead after k0 -> ctx8
  u16* wqkvb = (u16*)take(2304UL * 768 * 2);
  u16* wprojb = (u16*)take(768UL * 768 * 2);
  u16* projb = (u16*)take(256UL * 64 * 2);
  u16* qb = (u16*)take(96UL * 4096 * 64 * 2);   // 50.33 MB
  u16* kb = (u16*)take(96UL * 4096 * 64 * 2);   // 50.33 MB; dead after k3f -> attn
  u16* vT = (u16*)take(96UL * 64 * 4096 * 2);   // 50.33 MB
  float* kpart = (float*)take(96UL * 8 * 256 * 4);
  u32* mk = (u32*)take(256);
  u16* baug = (u16*)take(96UL * 80 * 256 * 2);
  float* bsum = (float*)take(96UL * 80 * 4);
  // stream-ordered aliases
  float* ctx8 = (float*)xb;  // 8*96*16384*4 B == 50.33 MB exactly
  u16* attn = kb;            // 50.33 MB

  k_init<<<1, 64, 0, stream>>>(mk);
  cvt_bf16<<<(25165824 / 4 + 255) / 256, 256, 0, stream>>>(x, xb, 25165824 / 4);
  cvt_bf16<<<(1769472 / 4 + 255) / 256, 256, 0, stream>>>(w_qkv, wqkvb, 1769472 / 4);
  cvt_bf16<<<(589824 / 4 + 255) / 256, 256, 0, stream>>>(w_proj, wprojb, 589824 / 4);
  cvt_bf16<<<(16384 / 4 + 255) / 256, 256, 0, stream>>>(proj, projb, 16384 / 4);
  k0_qkv<<<dim3(256, 18), 256, 0, stream>>>(xb, wqkvb, qb, kb, vT);
  k2_k1<<<dim3(64, 96), 256, 0, stream>>>(kb, projb, mk);
  k3f<<<dim3(8, 96), 256, 0, stream>>>(kb, vT, projb, mk, ctx8, kpart);
  k3b<<<96, 256, 0, stream>>>(ctx8, kpart, baug, bsum);
  k2q5<<<dim3(16, 96), 256, 0, stream>>>(qb, projb, baug, bsum, attn);
  k6_proj<<<dim3(256, 6), 256, 0, stream>>>(attn, wprojb, b_proj, out);
}

// Round 6
// 569.629 us; speedup vs baseline: 1.3284x; 1.2274x over previous
//
#include <hip/hip_runtime.h>
#include <hip/hip_bf16.h>

typedef __attribute__((ext_vector_type(4))) float f32x4;
typedef __attribute__((ext_vector_type(8))) short s16x8;
typedef __attribute__((ext_vector_type(4))) float f4v;
typedef __attribute__((ext_vector_type(4))) unsigned short us4;
typedef unsigned short u16;
typedef unsigned int u32;

#define H_ 12
#define NTOK 4096
#define DHEAD 64
#define MFEAT 256
#define CDIM 768

#define NORMALIZER 0.35355339059327373f  /* 64^-0.25 */
#define DIAGSCALE 0.0625f                /* 0.5 * NORMALIZER^2 */
#define RATIO_ 0.0625f                   /* 256^-0.5 */
#define EPS_ 1e-4f

#define MFMA(a, b, c) __builtin_amdgcn_mfma_f32_16x16x32_bf16((a), (b), (c), 0, 0, 0)

__device__ __forceinline__ float bf2f(u16 u) {
  union { float f; u32 v; } x; x.v = ((u32)u) << 16; return x.f;
}
__device__ __forceinline__ u16 f2bf(float f) {
  union { float f; u32 v; } x; x.f = f;
  u32 v = x.v + 0x7FFFu + ((x.v >> 16) & 1u);
  return (u16)(v >> 16);
}
__device__ __forceinline__ u32 fenc(float f) {
  u32 u = __float_as_uint(f);
  return (u & 0x80000000u) ? ~u : (u | 0x80000000u);
}
__device__ __forceinline__ float fdec(u32 k) {
  u32 u = (k & 0x80000000u) ? (k & 0x7fffffffu) : ~k;
  return __uint_as_float(u);
}
__device__ __forceinline__ void glds16(const u16* g, u16* l) {
  __builtin_amdgcn_global_load_lds((const __attribute__((address_space(1))) void*)g,
                                   (__attribute__((address_space(3))) void*)l, 16, 0, 0);
}

// write a wave's staged 64x64 bf16 tile (rows padded to 72) to dst
__device__ __forceinline__ void st_write64(const u16* stw, u16* dst, long ld, int lane) {
  int r0 = lane >> 3, cc = lane & 7;
#pragma unroll
  for (int c = 0; c < 8; ++c) {
    int row = c * 8 + r0;
    s16x8 v = *(const s16x8*)(stw + row * 72 + cc * 8);
    *(s16x8*)(dst + (long)row * ld + cc * 8) = v;
  }
}

__global__ void k_init(u32* mk) {
  if (threadIdx.x < 8) mk[threadIdx.x] = 0u;
}

__global__ void cvt_bf16(const float* __restrict__ in, u16* __restrict__ out, int n4) {
  int i = blockIdx.x * 256 + threadIdx.x;
  if (i >= n4) return;
  f4v v = *(const f4v*)(in + (long)i * 4);
  us4 o;
#pragma unroll
  for (int j = 0; j < 4; ++j) o[j] = f2bf(v[j]);
  *(us4*)(out + (long)i * 4) = o;
}

// ---------------- K0: QKV GEMM, glds16 staging (round-4 proven), identity block order ----------------
__global__ __launch_bounds__(256) void k0_qkv(const u16* __restrict__ A, const u16* __restrict__ Bm,
                                              u16* __restrict__ qb, u16* __restrict__ kb,
                                              u16* __restrict__ vT) {
  __shared__ u16 smem[4 * 64 * 72];   // loop: lA[0,4096) lB[4096,8192); epilogue: 4x 64x72
  u16* lA = smem;
  u16* lB = smem + 4096;
  int tid = threadIdx.x, lane = tid & 63, wid = tid >> 6;
  int m0 = blockIdx.x << 7, n0 = blockIdx.y << 7;
  int wr = (wid >> 1) << 6, wc = (wid & 1) << 6;
  int l15 = lane & 15, lk = lane >> 4;
  int u8 = (lk ^ ((l15 >> 2) & 3)) * 8;  // swizzled 16B unit for frag reads
  int pr = lane >> 2;
  int c0 = (((lane & 3) ^ ((pr >> 2) & 3))) * 8;  // pre-swizzled source col (u16)
  int rr0 = wid * 32 + pr, rr1 = rr0 + 16;
  const u16* Ab = A + (long)m0 * CDIM;
  const u16* Bb = Bm + (long)n0 * CDIM;
  const u16* ga0 = Ab + (long)rr0 * CDIM + c0;
  const u16* ga1 = Ab + (long)rr1 * CDIM + c0;
  const u16* gb0 = Bb + (long)rr0 * CDIM + c0;
  const u16* gb1 = Bb + (long)rr1 * CDIM + c0;
  u16* dA0 = lA + (wid * 2) * 512;
  u16* dA1 = lA + (wid * 2 + 1) * 512;
  u16* dB0 = lB + (wid * 2) * 512;
  u16* dB1 = lB + (wid * 2 + 1) * 512;
  f32x4 acc[4][4];
#pragma unroll
  for (int i = 0; i < 4; ++i)
#pragma unroll
    for (int j = 0; j < 4; ++j) acc[i][j] = (f32x4){0.f, 0.f, 0.f, 0.f};
  for (int k0 = 0; k0 < CDIM; k0 += 32) {
    __syncthreads();
    glds16(ga0 + k0, dA0);
    glds16(ga1 + k0, dA1);
    glds16(gb0 + k0, dB0);
    glds16(gb1 + k0, dB1);
    __syncthreads();
    s16x8 af[4], bv[4];
#pragma unroll
    for (int i = 0; i < 4; ++i) {
      af[i] = *(const s16x8*)(lA + (wr + i * 16 + l15) * 32 + u8);
      bv[i] = *(const s16x8*)(lB + (wc + i * 16 + l15) * 32 + u8);
    }
#pragma unroll
    for (int i = 0; i < 4; ++i)
#pragma unroll
      for (int j = 0; j < 4; ++j) acc[i][j] = MFMA(af[i], bv[j], acc[i][j]);
  }
  __syncthreads();  // before reusing smem as epilogue stage
  int colbase = n0 + wc;
  int qi = colbase / CDIM;
  int h = (colbase % CDIM) >> 6;
  int rowbase = m0 + wr;
  int b = rowbase >> 12;
  int nloc = rowbase & (NTOK - 1);
  u16* stw = smem + wid * 4608;
  if (qi < 2) {
#pragma unroll
    for (int i = 0; i < 4; ++i)
#pragma unroll
      for (int j = 0; j < 4; ++j)
#pragma unroll
        for (int r = 0; r < 4; ++r)
          stw[(i * 16 + lk * 4 + r) * 72 + j * 16 + l15] = f2bf(acc[i][j][r]);
    u16* dst = (qi == 0 ? qb : kb) + ((long)(b * H_ + h) * NTOK + nloc) * DHEAD;
    st_write64(stw, dst, DHEAD, lane);
  } else {
    // transposed stage: st[dd][n] (pack 4 r's into one b64)
#pragma unroll
    for (int i = 0; i < 4; ++i)
#pragma unroll
      for (int j = 0; j < 4; ++j) {
        us4 w;
#pragma unroll
        for (int r = 0; r < 4; ++r) w[r] = f2bf(acc[i][j][r]);
        *(us4*)(stw + (j * 16 + l15) * 72 + i * 16 + lk * 4) = w;
      }
    u16* dst = vT + (long)(b * H_ + h) * DHEAD * NTOK + nloc;
    st_write64(stw, dst, NTOK, lane);
  }
}

// ---------------- K2k pass1: global max of k_dash per batch ----------------
__global__ __launch_bounds__(256) void k2_k1(const u16* __restrict__ kb, const u16* __restrict__ projb,
                                             u32* __restrict__ mk) {
  __shared__ float wmax[4];
  int bh = blockIdx.y;
  int n0 = blockIdx.x << 6;
  const u16* Aq = kb + ((long)bh * NTOK + n0) * DHEAD;
  int tid = threadIdx.x, lane = tid & 63, wid = tid >> 6;
  int wc = wid << 6;
  int l15 = lane & 15, lk = lane >> 4;
  f32x4 acc[4][4];
#pragma unroll
  for (int i = 0; i < 4; ++i)
#pragma unroll
    for (int j = 0; j < 4; ++j) acc[i][j] = (f32x4){0.f, 0.f, 0.f, 0.f};
#pragma unroll
  for (int ks = 0; ks < 2; ++ks) {
    s16x8 a[4], bv[4];
#pragma unroll
    for (int i = 0; i < 4; ++i)
      a[i] = *(const s16x8*)(Aq + (long)(i * 16 + l15) * DHEAD + ks * 32 + lk * 8);
#pragma unroll
    for (int j = 0; j < 4; ++j)
      bv[j] = *(const s16x8*)(projb + (long)(wc + j * 16 + l15) * DHEAD + ks * 32 + lk * 8);
#pragma unroll
    for (int i = 0; i < 4; ++i)
#pragma unroll
      for (int j = 0; j < 4; ++j) acc[i][j] = MFMA(a[i], bv[j], acc[i][j]);
  }
  float m = -3.4e38f;
#pragma unroll
  for (int i = 0; i < 4; ++i)
#pragma unroll
    for (int j = 0; j < 4; ++j)
#pragma unroll
      for (int r = 0; r < 4; ++r) m = fmaxf(m, acc[i][j][r]);
  m = fmaxf(m, __shfl_xor(m, 1));
  m = fmaxf(m, __shfl_xor(m, 2));
  m = fmaxf(m, __shfl_xor(m, 4));
  m = fmaxf(m, __shfl_xor(m, 8));
  m = fmaxf(m, __shfl_xor(m, 16));
  m = fmaxf(m, __shfl_xor(m, 32));
  if (lane == 0) wmax[wid] = m;
  __syncthreads();
  if (tid == 0) {
    float mm = fmaxf(fmaxf(wmax[0], wmax[1]), fmaxf(wmax[2], wmax[3])) * NORMALIZER;
    atomicMax(mk + (blockIdx.y / H_), fenc(mm));
  }
}

// ---------------- K3f: fused phi(k) + context = k'^T @ v (512-token chunk, barrier-free) ----------------
// ctx8 layout: [nc][bh][dd][m]  (dd-major, coalesced for k3b)
__global__ __launch_bounds__(256) void k3f(const u16* __restrict__ kb, const u16* __restrict__ vT,
                                           const u16* __restrict__ projb, const u32* __restrict__ mk,
                                           float* __restrict__ ctx8, float* __restrict__ kpart) {
  __shared__ u16 smem[4 * 64 * 72];
  int bh = blockIdx.y, nc = blockIdx.x;  // nc in [0,8)
  int tid = threadIdx.x, lane = tid & 63, wid = tid >> 6;
  int l15 = lane & 15, lk = lane >> 4;
  int wc = wid << 6;
  float mg = fdec(mk[bh / H_]);
  const u16* Kb = kb + ((long)bh * NTOK + nc * 512) * DHEAD;
  const u16* Vb = vT + (long)bh * DHEAD * NTOK + nc * 512;
  u16* ktw = smem + wid * 4608;  // per-wave 9216B tile (wave-local!)
  f32x4 ctxa[4][4];
#pragma unroll
  for (int i = 0; i < 4; ++i)
#pragma unroll
    for (int j = 0; j < 4; ++j) ctxa[i][j] = (f32x4){0.f, 0.f, 0.f, 0.f};
  float cs[4] = {0.f, 0.f, 0.f, 0.f};
  for (int sb = 0; sb < 8; ++sb) {
    const u16* Ksb = Kb + sb * 64 * DHEAD;
    s16x8 a[4][2];
    float ss[4] = {0.f, 0.f, 0.f, 0.f};
#pragma unroll
    for (int i = 0; i < 4; ++i)
#pragma unroll
      for (int ks = 0; ks < 2; ++ks) {
        a[i][ks] = *(const s16x8*)(Ksb + (long)(i * 16 + l15) * DHEAD + ks * 32 + lk * 8);
#pragma unroll
        for (int e = 0; e < 8; ++e) { float f = bf2f((u16)a[i][ks][e]); ss[i] += f * f; }
      }
    float dgv[4];
#pragma unroll
    for (int i = 0; i < 4; ++i) {
      float s = ss[i];
      s += __shfl_xor(s, 16);
      s += __shfl_xor(s, 32);
      dgv[i] = s * DIAGSCALE;  // diag of token 16i+l15 (uniform over lk)
    }
    f32x4 dacc[4][4];
#pragma unroll
    for (int i = 0; i < 4; ++i)
#pragma unroll
      for (int j = 0; j < 4; ++j) dacc[i][j] = (f32x4){0.f, 0.f, 0.f, 0.f};
#pragma unroll
    for (int ks = 0; ks < 2; ++ks)
#pragma unroll
      for (int j = 0; j < 4; ++j) {
        s16x8 pb = *(const s16x8*)(projb + (long)(wc + j * 16 + l15) * DHEAD + ks * 32 + lk * 8);
#pragma unroll
        for (int i = 0; i < 4; ++i) dacc[i][j] = MFMA(a[i][ks], pb, dacc[i][j]);
      }
    // diag at token 16i+4lk+r via shuffle
    float dgr[4][4];
#pragma unroll
    for (int i = 0; i < 4; ++i)
#pragma unroll
      for (int r = 0; r < 4; ++r) dgr[i][r] = __shfl(dgv[i], 4 * lk + r);
    // phi -> kT (wave-local), packed b64 writes
#pragma unroll
    for (int i = 0; i < 4; ++i)
#pragma unroll
      for (int j = 0; j < 4; ++j) {
        us4 w;
#pragma unroll
        for (int r = 0; r < 4; ++r) {
          float v = RATIO_ * (__expf(dacc[i][j][r] * NORMALIZER - dgr[i][r] - mg) + EPS_);
          cs[j] += v;
          w[r] = f2bf(v);
        }
        *(us4*)(ktw + (j * 16 + l15) * 72 + i * 16 + lk * 4) = w;
      }
    // context MFMA: A = k'(features) rows from ktw, B = vT rows
#pragma unroll
    for (int ks = 0; ks < 2; ++ks) {
      s16x8 a2f[4], vb[4];
#pragma unroll
      for (int ii = 0; ii < 4; ++ii)
        a2f[ii] = *(const s16x8*)(ktw + (ii * 16 + l15) * 72 + ks * 32 + lk * 8);
#pragma unroll
      for (int jv = 0; jv < 4; ++jv)
        vb[jv] = *(const s16x8*)(Vb + (long)(jv * 16 + l15) * NTOK + sb * 64 + ks * 32 + lk * 8);
#pragma unroll
      for (int ii = 0; ii < 4; ++ii)
#pragma unroll
        for (int jv = 0; jv < 4; ++jv) ctxa[ii][jv] = MFMA(a2f[ii], vb[jv], ctxa[ii][jv]);
    }
  }
  asm volatile("" ::: "memory");  // fence u16/f32 LDS type-pun reordering
  // epilogue: transpose wave quadrant to [dd][m] via LDS (stride 68 f32), coalesced f32 writes
  float* lf = (float*)ktw;  // 32 x 68 f32 = 8704B <= 9216B
  float* dstb = ctx8 + (long)(nc * 96 + bh) * (MFEAT * DHEAD);
#pragma unroll
  for (int half = 0; half < 2; ++half) {
#pragma unroll
    for (int jh = 0; jh < 2; ++jh) {
      int jv = half * 2 + jh;
#pragma unroll
      for (int ii = 0; ii < 4; ++ii)
        *(f4v*)(lf + (jh * 16 + l15) * 68 + ii * 16 + lk * 4) =
            (f4v){ctxa[ii][jv][0], ctxa[ii][jv][1], ctxa[ii][jv][2], ctxa[ii][jv][3]};
    }
#pragma unroll
    for (int u = 0; u < 8; ++u) {
      int dd_l = u * 4 + lk;
      f4v v = *(const f4v*)(lf + dd_l * 68 + l15 * 4);
      *(f4v*)(dstb + (long)(half * 32 + dd_l) * MFEAT + wc + l15 * 4) = v;
    }
    asm volatile("" ::: "memory");
  }
#pragma unroll
  for (int j = 0; j < 4; ++j) {
    float s = cs[j];
    s += __shfl_xor(s, 16);
    s += __shfl_xor(s, 32);
    if (lk == 0) kpart[((long)bh * 8 + nc) * MFEAT + wc + j * 16 + l15] = s;
  }
}

// ---------------- K3b: Baug[bh][80][256] = [ctx^T ; k_sum ; 0] + f32 row-sums bsum[bh][80] ----------------
__global__ __launch_bounds__(256) void k3b(const float* __restrict__ ctx8, const float* __restrict__ kpart,
                                           u16* __restrict__ baug, float* __restrict__ bsum) {
  int bh = blockIdx.x, y = blockIdx.y;
  int tid = threadIdx.x;
  u16* o = baug + (long)bh * 80 * MFEAT;
  if (y < 4) {
    int dd = y * 16 + (tid >> 4);
    int m0 = (tid & 15) * 16;
    f4v s[4];
#pragma unroll
    for (int e = 0; e < 4; ++e) s[e] = (f4v){0.f, 0.f, 0.f, 0.f};
    for (int c = 0; c < 8; ++c) {
      const float* r = ctx8 + (long)(c * 96 + bh) * (MFEAT * DHEAD) + dd * MFEAT + m0;
#pragma unroll
      for (int e = 0; e < 4; ++e) s[e] += *(const f4v*)(r + e * 4);
    }
    float t = 0.f;
#pragma unroll
    for (int e = 0; e < 4; ++e) {
      us4 w;
#pragma unroll
      for (int q = 0; q < 4; ++q) { t += s[e][q]; w[q] = f2bf(s[e][q]); }
      *(us4*)(o + dd * MFEAT + m0 + e * 4) = w;
    }
    t += __shfl_xor(t, 1); t += __shfl_xor(t, 2); t += __shfl_xor(t, 4); t += __shfl_xor(t, 8);
    if ((tid & 15) == 0) bsum[bh * 80 + dd] = t;
  } else {
    __shared__ float red[4];
    int m = tid;
    float ks = 0.f;
    for (int c = 0; c < 8; ++c) ks += kpart[((long)bh * 8 + c) * MFEAT + m];
    o[64 * MFEAT + m] = f2bf(ks);
    float t = ks;
    t += __shfl_xor(t, 1); t += __shfl_xor(t, 2); t += __shfl_xor(t, 4);
    t += __shfl_xor(t, 8); t += __shfl_xor(t, 16); t += __shfl_xor(t, 32);
    if ((m & 63) == 0) red[m >> 6] = t;
    __syncthreads();
    if (m == 0) bsum[bh * 80 + 64] = red[0] + red[1] + red[2] + red[3];
    for (int dd = 65; dd < 80; ++dd) o[dd * MFEAT + m] = 0;
    if (m < 15) bsum[bh * 80 + 65 + m] = 0.f;
  }
}

// ---------------- K2Q5: fused phi(q) + (q' @ Baug^T), online max, analytic eps ----------------
__global__ __launch_bounds__(256) void k2q5(const u16* __restrict__ qb, const u16* __restrict__ projb,
                                            const u16* __restrict__ baug, const float* __restrict__ bsum,
                                            u16* __restrict__ attn) {
  __shared__ u16 smem[4 * 64 * 72];
  int bh = blockIdx.y;
  int b = bh / H_, h = bh % H_;
  int tid = threadIdx.x, lane = tid & 63, wid = tid >> 6;
  int l15 = lane & 15, lk = lane >> 4;
  int tb = blockIdx.x * 256 + wid * 64;  // wave's 64 tokens
  const u16* Aq = qb + ((long)bh * NTOK + tb) * DHEAD;
  const u16* Bb = baug + (long)bh * 80 * MFEAT;
  u16* qTw = smem + wid * 4608;  // loop: [64 tok][40]; epilogue: [64][72]

  // resident q fragments + diag (token = 16i+l15)
  s16x8 a2[4][2];
  float ssv[4] = {0.f, 0.f, 0.f, 0.f};
#pragma unroll
  for (int i = 0; i < 4; ++i)
#pragma unroll
    for (int ks = 0; ks < 2; ++ks) {
      a2[i][ks] = *(const s16x8*)(Aq + (long)(i * 16 + l15) * DHEAD + ks * 32 + lk * 8);
#pragma unroll
      for (int e = 0; e < 8; ++e) { float f = bf2f((u16)a2[i][ks][e]); ssv[i] += f * f; }
    }
  float dgv[4];
#pragma unroll
  for (int i = 0; i < 4; ++i) {
    float s = ssv[i];
    s += __shfl_xor(s, 16);
    s += __shfl_xor(s, 32);
    dgv[i] = s * DIAGSCALE;
  }
  float rm[4] = {-3.4e38f, -3.4e38f, -3.4e38f, -3.4e38f};
  f32x4 oacc[5][4];  // [baug-frag jo][token-frag i]; row=16jo+4lk+r, col(token)=16i+l15
#pragma unroll
  for (int jo = 0; jo < 5; ++jo)
#pragma unroll
    for (int i = 0; i < 4; ++i) oacc[jo][i] = (f32x4){0.f, 0.f, 0.f, 0.f};

  for (int c = 0; c < 8; ++c) {  // 32-feature chunks
    s16x8 pb[2][2];
#pragma unroll
    for (int j = 0; j < 2; ++j)
#pragma unroll
      for (int ks = 0; ks < 2; ++ks)
        pb[j][ks] = *(const s16x8*)(projb + (long)(c * 32 + j * 16 + l15) * DHEAD + ks * 32 + lk * 8);
    f32x4 dacc[2][4];
#pragma unroll
    for (int j = 0; j < 2; ++j)
#pragma unroll
      for (int i = 0; i < 4; ++i) dacc[j][i] = (f32x4){0.f, 0.f, 0.f, 0.f};
#pragma unroll
    for (int ks = 0; ks < 2; ++ks)
#pragma unroll
      for (int j = 0; j < 2; ++j)
#pragma unroll
        for (int i = 0; i < 4; ++i) dacc[j][i] = MFMA(pb[j][ks], a2[i][ks], dacc[j][i]);
    float fsc[4];
#pragma unroll
    for (int i = 0; i < 4; ++i) {
      float cm = dacc[0][i][0];
      cm = fmaxf(cm, dacc[0][i][1]); cm = fmaxf(cm, dacc[0][i][2]); cm = fmaxf(cm, dacc[0][i][3]);
      cm = fmaxf(cm, dacc[1][i][0]); cm = fmaxf(cm, dacc[1][i][1]);
      cm = fmaxf(cm, dacc[1][i][2]); cm = fmaxf(cm, dacc[1][i][3]);
      cm = fmaxf(cm, __shfl_xor(cm, 16));
      cm = fmaxf(cm, __shfl_xor(cm, 32));
      float rn = fmaxf(rm[i], cm);
      fsc[i] = __expf((rm[i] - rn) * NORMALIZER);
      rm[i] = rn;
    }
#pragma unroll
    for (int jo = 0; jo < 5; ++jo)
#pragma unroll
      for (int i = 0; i < 4; ++i) oacc[jo][i] *= fsc[i];
    // phi (NO eps -- handled analytically) -> wave-local LDS [64 tok][40]
#pragma unroll
    for (int i = 0; i < 4; ++i) {
      float dm = dgv[i] + rm[i] * NORMALIZER;
#pragma unroll
      for (int j = 0; j < 2; ++j) {
        us4 w;
#pragma unroll
        for (int r = 0; r < 4; ++r)
          w[r] = f2bf(RATIO_ * __expf(dacc[j][i][r] * NORMALIZER - dm));
        *(us4*)(qTw + (i * 16 + l15) * 40 + j * 16 + lk * 4) = w;
      }
    }
    s16x8 bB[5], qf[4];
#pragma unroll
    for (int jo = 0; jo < 5; ++jo)
      bB[jo] = *(const s16x8*)(Bb + (long)(jo * 16 + l15) * MFEAT + c * 32 + lk * 8);
#pragma unroll
    for (int i = 0; i < 4; ++i)
      qf[i] = *(const s16x8*)(qTw + (i * 16 + l15) * 40 + lk * 8);
#pragma unroll
    for (int jo = 0; jo < 5; ++jo)
#pragma unroll
      for (int i = 0; i < 4; ++i) oacc[jo][i] = MFMA(bB[jo], qf[i], oacc[jo][i]);
  }
  // analytic eps term: out += ratio*eps*rowsum(Baug[br]) (exact, unaffected by rescale)
#pragma unroll
  for (int jo = 0; jo < 5; ++jo) {
    f4v bs = *(const f4v*)(bsum + (long)bh * 80 + jo * 16 + lk * 4);
#pragma unroll
    for (int i = 0; i < 4; ++i)
#pragma unroll
      for (int r = 0; r < 4; ++r) oacc[jo][i][r] += (RATIO_ * EPS_) * bs[r];
  }
  // epilogue: divide by denominator, stage, write
  u16* stw = qTw;  // stride 72 now
#pragma unroll
  for (int i = 0; i < 4; ++i) {
    float dn = __shfl(oacc[4][i][0], l15);  // token 16i+l15's denom from lane (l15, lk=0)
    float inv = 1.0f / dn;
#pragma unroll
    for (int jo = 0; jo < 4; ++jo) {
      us4 w;
#pragma unroll
      for (int r = 0; r < 4; ++r) w[r] = f2bf(oacc[jo][i][r] * inv);
      *(us4*)(stw + (i * 16 + l15) * 72 + jo * 16 + lk * 4) = w;
    }
  }
  u16* dst = attn + ((long)b * NTOK + tb) * CDIM + h * DHEAD;
  st_write64(stw, dst, CDIM, lane);
}

// ---------------- K6: out = attn @ w_proj^T + b_proj (glds16, identity order, fp32 out) ----------------
__global__ __launch_bounds__(256) void k6_proj(const u16* __restrict__ A, const u16* __restrict__ Bm,
                                               const float* __restrict__ bproj, float* __restrict__ out) {
  __shared__ u16 smem[8192];
  u16* lA = smem;
  u16* lB = smem + 4096;
  int tid = threadIdx.x, lane = tid & 63, wid = tid >> 6;
  int m0 = blockIdx.x << 7, n0 = blockIdx.y << 7;
  int wr = (wid >> 1) << 6, wc = (wid & 1) << 6;
  int l15 = lane & 15, lk = lane >> 4;
  int u8 = (lk ^ ((l15 >> 2) & 3)) * 8;
  int pr = lane >> 2;
  int c0 = (((lane & 3) ^ ((pr >> 2) & 3))) * 8;
  int rr0 = wid * 32 + pr, rr1 = rr0 + 16;
  const u16* Ab = A + (long)m0 * CDIM;
  const u16* Bb = Bm + (long)n0 * CDIM;
  const u16* ga0 = Ab + (long)rr0 * CDIM + c0;
  const u16* ga1 = Ab + (long)rr1 * CDIM + c0;
  const u16* gb0 = Bb + (long)rr0 * CDIM + c0;
  const u16* gb1 = Bb + (long)rr1 * CDIM + c0;
  u16* dA0 = lA + (wid * 2) * 512;
  u16* dA1 = lA + (wid * 2 + 1) * 512;
  u16* dB0 = lB + (wid * 2) * 512;
  u16* dB1 = lB + (wid * 2 + 1) * 512;
  f32x4 acc[4][4];
#pragma unroll
  for (int i = 0; i < 4; ++i)
#pragma unroll
    for (int j = 0; j < 4; ++j) acc[i][j] = (f32x4){0.f, 0.f, 0.f, 0.f};
  for (int k0 = 0; k0 < CDIM; k0 += 32) {
    __syncthreads();
    glds16(ga0 + k0, dA0);
    glds16(ga1 + k0, dA1);
    glds16(gb0 + k0, dB0);
    glds16(gb1 + k0, dB1);
    __syncthreads();
    s16x8 af[4], bv[4];
#pragma unroll
    for (int i = 0; i < 4; ++i) {
      af[i] = *(const s16x8*)(lA + (wr + i * 16 + l15) * 32 + u8);
      bv[i] = *(const s16x8*)(lB + (wc + i * 16 + l15) * 32 + u8);
    }
#pragma unroll
    for (int i = 0; i < 4; ++i)
#pragma unroll
      for (int j = 0; j < 4; ++j) acc[i][j] = MFMA(af[i], bv[j], acc[i][j]);
  }
  float bpv[4];
#pragma unroll
  for (int j = 0; j < 4; ++j) bpv[j] = bproj[n0 + wc + j * 16 + l15];
#pragma unroll
  for (int i = 0; i < 4; ++i)
#pragma unroll
    for (int j = 0; j < 4; ++j)
#pragma unroll
      for (int r = 0; r < 4; ++r) {
        long row = m0 + wr + i * 16 + lk * 4 + r;
        int col = n0 + wc + j * 16 + l15;
        out[row * CDIM + col] = acc[i][j][r] + bpv[j];
      }
}

extern "C" void kernel_launch(void* const* d_in, const int* in_sizes, int n_in,
                              void* d_out, int out_size, void* d_ws, size_t ws_size,
                              hipStream_t stream) {
  const float* x = (const float*)d_in[0];
  const float* w_qkv = (const float*)d_in[1];
  const float* w_proj = (const float*)d_in[2];
  const float* b_proj = (const float*)d_in[3];
  const float* proj = (const float*)d_in[4];
  float* out = (float*)d_out;

  char* p = (char*)d_ws;
  auto take = [&](size_t bytes) {
    char* r = p;
    p += (bytes + 255) & ~(size_t)255;
    return r;
  };
  u16* xb = (u16*)take(32768UL * 768 * 2);      // 50.33 MB; dead after k0 -> ctx8
  u16* wqkvb = (u16*)take(2304UL * 768 * 2);
  u16* wprojb = (u16*)take(768UL * 768 * 2);
  u16* projb = (u16*)take(256UL * 64 * 2);
  u16* qb = (u16*)take(96UL * 4096 * 64 * 2);   // 50.33 MB
  u16* kb = (u16*)take(96UL * 4096 * 64 * 2);   // 50.33 MB; dead after k3f -> attn
  u16* vT = (u16*)take(96UL * 64 * 4096 * 2);   // 50.33 MB
  float* kpart = (float*)take(96UL * 8 * 256 * 4);
  u32* mk = (u32*)take(256);
  u16* baug = (u16*)take(96UL * 80 * 256 * 2);
  float* bsum = (float*)take(96UL * 80 * 4);
  // stream-ordered aliases
  float* ctx8 = (float*)xb;  // [8][96][64][256] f32 == 50.33 MB exactly
  u16* attn = kb;            // 50.33 MB

  k_init<<<1, 64, 0, stream>>>(mk);
  cvt_bf16<<<(25165824 / 4 + 255) / 256, 256, 0, stream>>>(x, xb, 25165824 / 4);
  cvt_bf16<<<(1769472 / 4 + 255) / 256, 256, 0, stream>>>(w_qkv, wqkvb, 1769472 / 4);
  cvt_bf16<<<(589824 / 4 + 255) / 256, 256, 0, stream>>>(w_proj, wprojb, 589824 / 4);
  cvt_bf16<<<(16384 / 4 + 255) / 256, 256, 0, stream>>>(proj, projb, 16384 / 4);
  k0_qkv<<<dim3(256, 18), 256, 0, stream>>>(xb, wqkvb, qb, kb, vT);
  k2_k1<<<dim3(64, 96), 256, 0, stream>>>(kb, projb, mk);
  k3f<<<dim3(8, 96), 256, 0, stream>>>(kb, vT, projb, mk, ctx8, kpart);
  k3b<<<dim3(96, 5), 256, 0, stream>>>(ctx8, kpart, baug, bsum);
  k2q5<<<dim3(16, 96), 256, 0, stream>>>(qb, projb, baug, bsum, attn);
  k6_proj<<<dim3(256, 6), 256, 0, stream>>>(attn, wprojb, b_proj, out);
}

// Round 8
// 549.001 us; speedup vs baseline: 1.3783x; 1.0376x over previous
//
#include <hip/hip_runtime.h>
#include <hip/hip_bf16.h>

typedef __attribute__((ext_vector_type(4))) float f32x4;
typedef __attribute__((ext_vector_type(8))) short s16x8;
typedef __attribute__((ext_vector_type(4))) float f4v;
typedef __attribute__((ext_vector_type(4))) unsigned short us4;
typedef unsigned short u16;
typedef unsigned int u32;

#define H_ 12
#define NTOK 4096
#define DHEAD 64
#define MFEAT 256
#define CDIM 768

#define NORMALIZER 0.35355339059327373f  /* 64^-0.25 */
#define DIAGSCALE 0.0625f                /* 0.5 * NORMALIZER^2 */
#define RATIO_ 0.0625f                   /* 256^-0.5 */
#define EPS_ 1e-4f

#define MFMA(a, b, c) __builtin_amdgcn_mfma_f32_16x16x32_bf16((a), (b), (c), 0, 0, 0)

__device__ __forceinline__ float bf2f(u16 u) {
  union { float f; u32 v; } x; x.v = ((u32)u) << 16; return x.f;
}
__device__ __forceinline__ u16 f2bf(float f) {
  union { float f; u32 v; } x; x.f = f;
  u32 v = x.v + 0x7FFFu + ((x.v >> 16) & 1u);
  return (u16)(v >> 16);
}
__device__ __forceinline__ u32 fenc(float f) {
  u32 u = __float_as_uint(f);
  return (u & 0x80000000u) ? ~u : (u | 0x80000000u);
}
__device__ __forceinline__ float fdec(u32 k) {
  u32 u = (k & 0x80000000u) ? (k & 0x7fffffffu) : ~k;
  return __uint_as_float(u);
}
__device__ __forceinline__ void glds16(const u16* g, u16* l) {
  __builtin_amdgcn_global_load_lds((const __attribute__((address_space(1))) void*)g,
                                   (__attribute__((address_space(3))) void*)l, 16, 0, 0);
}

// write a wave's staged 64x64 bf16 tile (rows padded to 72) to dst
__device__ __forceinline__ void st_write64(const u16* stw, u16* dst, long ld, int lane) {
  int r0 = lane >> 3, cc = lane & 7;
#pragma unroll
  for (int c = 0; c < 8; ++c) {
    int row = c * 8 + r0;
    s16x8 v = *(const s16x8*)(stw + row * 72 + cc * 8);
    *(s16x8*)(dst + (long)row * ld + cc * 8) = v;
  }
}

__global__ void k_init(u32* mk) {
  if (threadIdx.x < 8) mk[threadIdx.x] = 0u;
}

__global__ void cvt_bf16(const float* __restrict__ in, u16* __restrict__ out, int n4) {
  int i = blockIdx.x * 256 + threadIdx.x;
  if (i >= n4) return;
  f4v v = *(const f4v*)(in + (long)i * 4);
  us4 o;
#pragma unroll
  for (int j = 0; j < 4; ++j) o[j] = f2bf(v[j]);
  *(us4*)(out + (long)i * 4) = o;
}

// ---------------- K0: QKV GEMM, BK=64 single-buffer glds16, L2-friendly grid order ----------------
// grid = (18, 256): bx = N-panel (w_qkv rows), by = M-panel (tokens). Consecutive blocks
// share one 0.2MB A-panel and sweep B (3.5MB, L2-resident).
__global__ __launch_bounds__(256) void k0_qkv(const u16* __restrict__ A, const u16* __restrict__ Bm,
                                              u16* __restrict__ qb, u16* __restrict__ kb,
                                              u16* __restrict__ vT) {
  __shared__ u16 smem[4 * 64 * 72];   // loop: lA[0,8192) lB[8192,16384) u16; epilogue: 4x 64x72
  u16* lA = smem;
  u16* lB = smem + 8192;
  int tid = threadIdx.x, lane = tid & 63, wid = tid >> 6;
  int m0 = blockIdx.y << 7, n0 = blockIdx.x << 7;
  int wr = (wid >> 1) << 6, wc = (wid & 1) << 6;
  int l15 = lane & 15, lk = lane >> 4;
  // staging: wave w covers rows w*32..w*32+31 of A and B tiles (4 glds16 each)
  int lr = lane >> 3;            // row within 8-row group
  int lu = (lane & 7) ^ lr;      // pre-swizzled source 16B-unit: lds[row][u]=glob[row][u^(row&7)]
  const u16* Ab = A + (long)m0 * CDIM;
  const u16* Bb = Bm + (long)n0 * CDIM;
  const u16* gA = Ab + (long)(wid * 32 + lr) * CDIM + lu * 8;
  const u16* gB = Bb + (long)(wid * 32 + lr) * CDIM + lu * 8;
  u16* dA = lA + wid * 2048;
  u16* dB = lB + wid * 2048;
  f32x4 acc[4][4];
#pragma unroll
  for (int i = 0; i < 4; ++i)
#pragma unroll
    for (int j = 0; j < 4; ++j) acc[i][j] = (f32x4){0.f, 0.f, 0.f, 0.f};
  for (int k0 = 0; k0 < CDIM; k0 += 64) {
    __syncthreads();
#pragma unroll
    for (int g = 0; g < 4; ++g) {
      glds16(gA + k0 + (long)g * 8 * CDIM, dA + g * 512);
      glds16(gB + k0 + (long)g * 8 * CDIM, dB + g * 512);
    }
    __syncthreads();
#pragma unroll
    for (int ks = 0; ks < 2; ++ks) {
      s16x8 af[4], bv[4];
#pragma unroll
      for (int i = 0; i < 4; ++i) {
        int co = ((ks * 4 + lk) ^ (l15 & 7)) * 8;   // swizzled read unit
        af[i] = *(const s16x8*)(lA + (wr + i * 16 + l15) * 64 + co);
        bv[i] = *(const s16x8*)(lB + (wc + i * 16 + l15) * 64 + co);
      }
#pragma unroll
      for (int i = 0; i < 4; ++i)
#pragma unroll
        for (int j = 0; j < 4; ++j) acc[i][j] = MFMA(af[i], bv[j], acc[i][j]);
    }
  }
  __syncthreads();  // before reusing smem as epilogue stage
  int colbase = n0 + wc;
  int qi = colbase / CDIM;
  int h = (colbase % CDIM) >> 6;
  int rowbase = m0 + wr;
  int b = rowbase >> 12;
  int nloc = rowbase & (NTOK - 1);
  u16* stw = smem + wid * 4608;
  if (qi < 2) {
#pragma unroll
    for (int i = 0; i < 4; ++i)
#pragma unroll
      for (int j = 0; j < 4; ++j)
#pragma unroll
        for (int r = 0; r < 4; ++r)
          stw[(i * 16 + lk * 4 + r) * 72 + j * 16 + l15] = f2bf(acc[i][j][r]);
    u16* dst = (qi == 0 ? qb : kb) + ((long)(b * H_ + h) * NTOK + nloc) * DHEAD;
    st_write64(stw, dst, DHEAD, lane);
  } else {
    // transposed stage: st[dd][n] (pack 4 r's into one b64)
#pragma unroll
    for (int i = 0; i < 4; ++i)
#pragma unroll
      for (int j = 0; j < 4; ++j) {
        us4 w;
#pragma unroll
        for (int r = 0; r < 4; ++r) w[r] = f2bf(acc[i][j][r]);
        *(us4*)(stw + (j * 16 + l15) * 72 + i * 16 + lk * 4) = w;
      }
    u16* dst = vT + (long)(b * H_ + h) * DHEAD * NTOK + nloc;
    st_write64(stw, dst, NTOK, lane);
  }
}

// ---------------- K2k pass1: global max of k_dash per batch ----------------
__global__ __launch_bounds__(256) void k2_k1(const u16* __restrict__ kb, const u16* __restrict__ projb,
                                             u32* __restrict__ mk) {
  __shared__ float wmax[4];
  int bh = blockIdx.y;
  int n0 = blockIdx.x << 6;
  const u16* Aq = kb + ((long)bh * NTOK + n0) * DHEAD;
  int tid = threadIdx.x, lane = tid & 63, wid = tid >> 6;
  int wc = wid << 6;
  int l15 = lane & 15, lk = lane >> 4;
  f32x4 acc[4][4];
#pragma unroll
  for (int i = 0; i < 4; ++i)
#pragma unroll
    for (int j = 0; j < 4; ++j) acc[i][j] = (f32x4){0.f, 0.f, 0.f, 0.f};
#pragma unroll
  for (int ks = 0; ks < 2; ++ks) {
    s16x8 a[4], bv[4];
#pragma unroll
    for (int i = 0; i < 4; ++i)
      a[i] = *(const s16x8*)(Aq + (long)(i * 16 + l15) * DHEAD + ks * 32 + lk * 8);
#pragma unroll
    for (int j = 0; j < 4; ++j)
      bv[j] = *(const s16x8*)(projb + (long)(wc + j * 16 + l15) * DHEAD + ks * 32 + lk * 8);
#pragma unroll
    for (int i = 0; i < 4; ++i)
#pragma unroll
      for (int j = 0; j < 4; ++j) acc[i][j] = MFMA(a[i], bv[j], acc[i][j]);
  }
  float m = -3.4e38f;
#pragma unroll
  for (int i = 0; i < 4; ++i)
#pragma unroll
    for (int j = 0; j < 4; ++j)
#pragma unroll
      for (int r = 0; r < 4; ++r) m = fmaxf(m, acc[i][j][r]);
  m = fmaxf(m, __shfl_xor(m, 1));
  m = fmaxf(m, __shfl_xor(m, 2));
  m = fmaxf(m, __shfl_xor(m, 4));
  m = fmaxf(m, __shfl_xor(m, 8));
  m = fmaxf(m, __shfl_xor(m, 16));
  m = fmaxf(m, __shfl_xor(m, 32));
  if (lane == 0) wmax[wid] = m;
  __syncthreads();
  if (tid == 0) {
    float mm = fmaxf(fmaxf(wmax[0], wmax[1]), fmaxf(wmax[2], wmax[3])) * NORMALIZER;
    atomicMax(mk + (blockIdx.y / H_), fenc(mm));
  }
}

// ---------------- K3f: fused phi(k) + context = k'^T @ v (512-token chunk, barrier-free) ----------------
// ctx8 layout: [nc][bh][dd][m]  (dd-major, coalesced for k3b)
__global__ __launch_bounds__(256) void k3f(const u16* __restrict__ kb, const u16* __restrict__ vT,
                                           const u16* __restrict__ projb, const u32* __restrict__ mk,
                                           float* __restrict__ ctx8, float* __restrict__ kpart) {
  __shared__ u16 smem[4 * 64 * 72];
  int bh = blockIdx.y, nc = blockIdx.x;  // nc in [0,8)
  int tid = threadIdx.x, lane = tid & 63, wid = tid >> 6;
  int l15 = lane & 15, lk = lane >> 4;
  int wc = wid << 6;
  float mg = fdec(mk[bh / H_]);
  const u16* Kb = kb + ((long)bh * NTOK + nc * 512) * DHEAD;
  const u16* Vb = vT + (long)bh * DHEAD * NTOK + nc * 512;
  u16* ktw = smem + wid * 4608;  // per-wave 9216B tile (wave-local!)
  f32x4 ctxa[4][4];
#pragma unroll
  for (int i = 0; i < 4; ++i)
#pragma unroll
    for (int j = 0; j < 4; ++j) ctxa[i][j] = (f32x4){0.f, 0.f, 0.f, 0.f};
  float cs[4] = {0.f, 0.f, 0.f, 0.f};
  for (int sb = 0; sb < 8; ++sb) {
    const u16* Ksb = Kb + sb * 64 * DHEAD;
    s16x8 a[4][2];
    float ss[4] = {0.f, 0.f, 0.f, 0.f};
#pragma unroll
    for (int i = 0; i < 4; ++i)
#pragma unroll
      for (int ks = 0; ks < 2; ++ks) {
        a[i][ks] = *(const s16x8*)(Ksb + (long)(i * 16 + l15) * DHEAD + ks * 32 + lk * 8);
#pragma unroll
        for (int e = 0; e < 8; ++e) { float f = bf2f((u16)a[i][ks][e]); ss[i] += f * f; }
      }
    float dgv[4];
#pragma unroll
    for (int i = 0; i < 4; ++i) {
      float s = ss[i];
      s += __shfl_xor(s, 16);
      s += __shfl_xor(s, 32);
      dgv[i] = s * DIAGSCALE;  // diag of token 16i+l15 (uniform over lk)
    }
    f32x4 dacc[4][4];
#pragma unroll
    for (int i = 0; i < 4; ++i)
#pragma unroll
      for (int j = 0; j < 4; ++j) dacc[i][j] = (f32x4){0.f, 0.f, 0.f, 0.f};
#pragma unroll
    for (int ks = 0; ks < 2; ++ks)
#pragma unroll
      for (int j = 0; j < 4; ++j) {
        s16x8 pb = *(const s16x8*)(projb + (long)(wc + j * 16 + l15) * DHEAD + ks * 32 + lk * 8);
#pragma unroll
        for (int i = 0; i < 4; ++i) dacc[i][j] = MFMA(a[i][ks], pb, dacc[i][j]);
      }
    // diag at token 16i+4lk+r via shuffle
    float dgr[4][4];
#pragma unroll
    for (int i = 0; i < 4; ++i)
#pragma unroll
      for (int r = 0; r < 4; ++r) dgr[i][r] = __shfl(dgv[i], 4 * lk + r);
    // phi -> kT (wave-local), packed b64 writes
#pragma unroll
    for (int i = 0; i < 4; ++i)
#pragma unroll
      for (int j = 0; j < 4; ++j) {
        us4 w;
#pragma unroll
        for (int r = 0; r < 4; ++r) {
          float v = RATIO_ * (__expf(dacc[i][j][r] * NORMALIZER - dgr[i][r] - mg) + EPS_);
          cs[j] += v;
          w[r] = f2bf(v);
        }
        *(us4*)(ktw + (j * 16 + l15) * 72 + i * 16 + lk * 4) = w;
      }
    // context MFMA: A = k'(features) rows from ktw, B = vT rows
#pragma unroll
    for (int ks = 0; ks < 2; ++ks) {
      s16x8 a2f[4], vb[4];
#pragma unroll
      for (int ii = 0; ii < 4; ++ii)
        a2f[ii] = *(const s16x8*)(ktw + (ii * 16 + l15) * 72 + ks * 32 + lk * 8);
#pragma unroll
      for (int jv = 0; jv < 4; ++jv)
        vb[jv] = *(const s16x8*)(Vb + (long)(jv * 16 + l15) * NTOK + sb * 64 + ks * 32 + lk * 8);
#pragma unroll
      for (int ii = 0; ii < 4; ++ii)
#pragma unroll
        for (int jv = 0; jv < 4; ++jv) ctxa[ii][jv] = MFMA(a2f[ii], vb[jv], ctxa[ii][jv]);
    }
  }
  asm volatile("" ::: "memory");  // fence u16/f32 LDS type-pun reordering
  // epilogue: transpose wave quadrant to [dd][m] via LDS (stride 68 f32), coalesced f32 writes
  float* lf = (float*)ktw;  // 32 x 68 f32 = 8704B <= 9216B
  float* dstb = ctx8 + (long)(nc * 96 + bh) * (MFEAT * DHEAD);
#pragma unroll
  for (int half = 0; half < 2; ++half) {
#pragma unroll
    for (int jh = 0; jh < 2; ++jh) {
      int jv = half * 2 + jh;
#pragma unroll
      for (int ii = 0; ii < 4; ++ii)
        *(f4v*)(lf + (jh * 16 + l15) * 68 + ii * 16 + lk * 4) =
            (f4v){ctxa[ii][jv][0], ctxa[ii][jv][1], ctxa[ii][jv][2], ctxa[ii][jv][3]};
    }
#pragma unroll
    for (int u = 0; u < 8; ++u) {
      int dd_l = u * 4 + lk;
      f4v v = *(const f4v*)(lf + dd_l * 68 + l15 * 4);
      *(f4v*)(dstb + (long)(half * 32 + dd_l) * MFEAT + wc + l15 * 4) = v;
    }
    asm volatile("" ::: "memory");
  }
#pragma unroll
  for (int j = 0; j < 4; ++j) {
    float s = cs[j];
    s += __shfl_xor(s, 16);
    s += __shfl_xor(s, 32);
    if (lk == 0) kpart[((long)bh * 8 + nc) * MFEAT + wc + j * 16 + l15] = s;
  }
}

// ---------------- K3b: Baug[bh][80][256] = [ctx^T ; k_sum ; 0] + f32 row-sums bsum[bh][80] ----------------
__global__ __launch_bounds__(256) void k3b(const float* __restrict__ ctx8, const float* __restrict__ kpart,
                                           u16* __restrict__ baug, float* __restrict__ bsum) {
  int bh = blockIdx.x, y = blockIdx.y;
  int tid = threadIdx.x;
  u16* o = baug + (long)bh * 80 * MFEAT;
  if (y < 4) {
    int dd = y * 16 + (tid >> 4);
    int m0 = (tid & 15) * 16;
    f4v s[4];
#pragma unroll
    for (int e = 0; e < 4; ++e) s[e] = (f4v){0.f, 0.f, 0.f, 0.f};
    for (int c = 0; c < 8; ++c) {
      const float* r = ctx8 + (long)(c * 96 + bh) * (MFEAT * DHEAD) + dd * MFEAT + m0;
#pragma unroll
      for (int e = 0; e < 4; ++e) s[e] += *(const f4v*)(r + e * 4);
    }
    float t = 0.f;
#pragma unroll
    for (int e = 0; e < 4; ++e) {
      us4 w;
#pragma unroll
      for (int q = 0; q < 4; ++q) { t += s[e][q]; w[q] = f2bf(s[e][q]); }
      *(us4*)(o + dd * MFEAT + m0 + e * 4) = w;
    }
    t += __shfl_xor(t, 1); t += __shfl_xor(t, 2); t += __shfl_xor(t, 4); t += __shfl_xor(t, 8);
    if ((tid & 15) == 0) bsum[bh * 80 + dd] = t;
  } else {
    __shared__ float red[4];
    int m = tid;
    float ks = 0.f;
    for (int c = 0; c < 8; ++c) ks += kpart[((long)bh * 8 + c) * MFEAT + m];
    o[64 * MFEAT + m] = f2bf(ks);
    float t = ks;
    t += __shfl_xor(t, 1); t += __shfl_xor(t, 2); t += __shfl_xor(t, 4);
    t += __shfl_xor(t, 8); t += __shfl_xor(t, 16); t += __shfl_xor(t, 32);
    if ((m & 63) == 0) red[m >> 6] = t;
    __syncthreads();
    if (m == 0) bsum[bh * 80 + 64] = red[0] + red[1] + red[2] + red[3];
    for (int dd = 65; dd < 80; ++dd) o[dd * MFEAT + m] = 0;
    if (m < 15) bsum[bh * 80 + 65 + m] = 0.f;
  }
}

// ---------------- K2Q5: fused phi(q) + (q' @ Baug^T), online max, analytic eps ----------------
__global__ __launch_bounds__(256) void k2q5(const u16* __restrict__ qb, const u16* __restrict__ projb,
                                            const u16* __restrict__ baug, const float* __restrict__ bsum,
                                            u16* __restrict__ attn) {
  __shared__ u16 smem[4 * 64 * 72];
  int bh = blockIdx.y;
  int b = bh / H_, h = bh % H_;
  int tid = threadIdx.x, lane = tid & 63, wid = tid >> 6;
  int l15 = lane & 15, lk = lane >> 4;
  int tb = blockIdx.x * 256 + wid * 64;  // wave's 64 tokens
  const u16* Aq = qb + ((long)bh * NTOK + tb) * DHEAD;
  const u16* Bb = baug + (long)bh * 80 * MFEAT;
  u16* qTw = smem + wid * 4608;  // loop: [64 tok][40]; epilogue: [64][72]

  // resident q fragments + diag (token = 16i+l15)
  s16x8 a2[4][2];
  float ssv[4] = {0.f, 0.f, 0.f, 0.f};
#pragma unroll
  for (int i = 0; i < 4; ++i)
#pragma unroll
    for (int ks = 0; ks < 2; ++ks) {
      a2[i][ks] = *(const s16x8*)(Aq + (long)(i * 16 + l15) * DHEAD + ks * 32 + lk * 8);
#pragma unroll
      for (int e = 0; e < 8; ++e) { float f = bf2f((u16)a2[i][ks][e]); ssv[i] += f * f; }
    }
  float dgv[4];
#pragma unroll
  for (int i = 0; i < 4; ++i) {
    float s = ssv[i];
    s += __shfl_xor(s, 16);
    s += __shfl_xor(s, 32);
    dgv[i] = s * DIAGSCALE;
  }
  float rm[4] = {-3.4e38f, -3.4e38f, -3.4e38f, -3.4e38f};
  f32x4 oacc[5][4];  // [baug-frag jo][token-frag i]; row=16jo+4lk+r, col(token)=16i+l15
#pragma unroll
  for (int jo = 0; jo < 5; ++jo)
#pragma unroll
    for (int i = 0; i < 4; ++i) oacc[jo][i] = (f32x4){0.f, 0.f, 0.f, 0.f};

  for (int c = 0; c < 8; ++c) {  // 32-feature chunks
    s16x8 pb[2][2];
#pragma unroll
    for (int j = 0; j < 2; ++j)
#pragma unroll
      for (int ks = 0; ks < 2; ++ks)
        pb[j][ks] = *(const s16x8*)(projb + (long)(c * 32 + j * 16 + l15) * DHEAD + ks * 32 + lk * 8);
    f32x4 dacc[2][4];
#pragma unroll
    for (int j = 0; j < 2; ++j)
#pragma unroll
      for (int i = 0; i < 4; ++i) dacc[j][i] = (f32x4){0.f, 0.f, 0.f, 0.f};
#pragma unroll
    for (int ks = 0; ks < 2; ++ks)
#pragma unroll
      for (int j = 0; j < 2; ++j)
#pragma unroll
        for (int i = 0; i < 4; ++i) dacc[j][i] = MFMA(pb[j][ks], a2[i][ks], dacc[j][i]);
    float fsc[4];
#pragma unroll
    for (int i = 0; i < 4; ++i) {
      float cm = dacc[0][i][0];
      cm = fmaxf(cm, dacc[0][i][1]); cm = fmaxf(cm, dacc[0][i][2]); cm = fmaxf(cm, dacc[0][i][3]);
      cm = fmaxf(cm, dacc[1][i][0]); cm = fmaxf(cm, dacc[1][i][1]);
      cm = fmaxf(cm, dacc[1][i][2]); cm = fmaxf(cm, dacc[1][i][3]);
      cm = fmaxf(cm, __shfl_xor(cm, 16));
      cm = fmaxf(cm, __shfl_xor(cm, 32));
      float rn = fmaxf(rm[i], cm);
      fsc[i] = __expf((rm[i] - rn) * NORMALIZER);
      rm[i] = rn;
    }
#pragma unroll
    for (int jo = 0; jo < 5; ++jo)
#pragma unroll
      for (int i = 0; i < 4; ++i) oacc[jo][i] *= fsc[i];
    // phi (NO eps -- handled analytically) -> wave-local LDS [64 tok][40]
#pragma unroll
    for (int i = 0; i < 4; ++i) {
      float dm = dgv[i] + rm[i] * NORMALIZER;
#pragma unroll
      for (int j = 0; j < 2; ++j) {
        us4 w;
#pragma unroll
        for (int r = 0; r < 4; ++r)
          w[r] = f2bf(RATIO_ * __expf(dacc[j][i][r] * NORMALIZER - dm));
        *(us4*)(qTw + (i * 16 + l15) * 40 + j * 16 + lk * 4) = w;
      }
    }
    s16x8 bB[5], qf[4];
#pragma unroll
    for (int jo = 0; jo < 5; ++jo)
      bB[jo] = *(const s16x8*)(Bb + (long)(jo * 16 + l15) * MFEAT + c * 32 + lk * 8);
#pragma unroll
    for (int i = 0; i < 4; ++i)
      qf[i] = *(const s16x8*)(qTw + (i * 16 + l15) * 40 + lk * 8);
#pragma unroll
    for (int jo = 0; jo < 5; ++jo)
#pragma unroll
      for (int i = 0; i < 4; ++i) oacc[jo][i] = MFMA(bB[jo], qf[i], oacc[jo][i]);
  }
  // analytic eps term: out += ratio*eps*rowsum(Baug[br]) (exact, unaffected by rescale)
#pragma unroll
  for (int jo = 0; jo < 5; ++jo) {
    f4v bs = *(const f4v*)(bsum + (long)bh * 80 + jo * 16 + lk * 4);
#pragma unroll
    for (int i = 0; i < 4; ++i)
#pragma unroll
      for (int r = 0; r < 4; ++r) oacc[jo][i][r] += (RATIO_ * EPS_) * bs[r];
  }
  // epilogue: divide by denominator, stage, write
  u16* stw = qTw;  // stride 72 now
#pragma unroll
  for (int i = 0; i < 4; ++i) {
    float dn = __shfl(oacc[4][i][0], l15);  // token 16i+l15's denom from lane (l15, lk=0)
    float inv = 1.0f / dn;
#pragma unroll
    for (int jo = 0; jo < 4; ++jo) {
      us4 w;
#pragma unroll
      for (int r = 0; r < 4; ++r) w[r] = f2bf(oacc[jo][i][r] * inv);
      *(us4*)(stw + (i * 16 + l15) * 72 + jo * 16 + lk * 4) = w;
    }
  }
  u16* dst = attn + ((long)b * NTOK + tb) * CDIM + h * DHEAD;
  st_write64(stw, dst, CDIM, lane);
}

// ---------------- K6: out = attn @ w_proj^T + b_proj (BK=64, L2-friendly grid, fp32 out) ----------------
// grid = (6, 256): bx = N-panel (w_proj rows, 1.2MB L2-resident), by = M-panel (tokens).
__global__ __launch_bounds__(256) void k6_proj(const u16* __restrict__ A, const u16* __restrict__ Bm,
                                               const float* __restrict__ bproj, float* __restrict__ out) {
  __shared__ u16 smem[16384];  // lA[0,8192) lB[8192,16384)
  u16* lA = smem;
  u16* lB = smem + 8192;
  int tid = threadIdx.x, lane = tid & 63, wid = tid >> 6;
  int m0 = blockIdx.y << 7, n0 = blockIdx.x << 7;
  int wr = (wid >> 1) << 6, wc = (wid & 1) << 6;
  int l15 = lane & 15, lk = lane >> 4;
  int lr = lane >> 3;
  int lu = (lane & 7) ^ lr;
  const u16* Ab = A + (long)m0 * CDIM;
  const u16* Bb = Bm + (long)n0 * CDIM;
  const u16* gA = Ab + (long)(wid * 32 + lr) * CDIM + lu * 8;
  const u16* gB = Bb + (long)(wid * 32 + lr) * CDIM + lu * 8;
  u16* dA = lA + wid * 2048;
  u16* dB = lB + wid * 2048;
  f32x4 acc[4][4];
#pragma unroll
  for (int i = 0; i < 4; ++i)
#pragma unroll
    for (int j = 0; j < 4; ++j) acc[i][j] = (f32x4){0.f, 0.f, 0.f, 0.f};
  for (int k0 = 0; k0 < CDIM; k0 += 64) {
    __syncthreads();
#pragma unroll
    for (int g = 0; g < 4; ++g) {
      glds16(gA + k0 + (long)g * 8 * CDIM, dA + g * 512);
      glds16(gB + k0 + (long)g * 8 * CDIM, dB + g * 512);
    }
    __syncthreads();
#pragma unroll
    for (int ks = 0; ks < 2; ++ks) {
      s16x8 af[4], bv[4];
#pragma unroll
      for (int i = 0; i < 4; ++i) {
        int co = ((ks * 4 + lk) ^ (l15 & 7)) * 8;
        af[i] = *(const s16x8*)(lA + (wr + i * 16 + l15) * 64 + co);
        bv[i] = *(const s16x8*)(lB + (wc + i * 16 + l15) * 64 + co);
      }
#pragma unroll
      for (int i = 0; i < 4; ++i)
#pragma unroll
        for (int j = 0; j < 4; ++j) acc[i][j] = MFMA(af[i], bv[j], acc[i][j]);
    }
  }
  float bpv[4];
#pragma unroll
  for (int j = 0; j < 4; ++j) bpv[j] = bproj[n0 + wc + j * 16 + l15];
#pragma unroll
  for (int i = 0; i < 4; ++i)
#pragma unroll
    for (int j = 0; j < 4; ++j)
#pragma unroll
      for (int r = 0; r < 4; ++r) {
        long row = m0 + wr + i * 16 + lk * 4 + r;
        int col = n0 + wc + j * 16 + l15;
        out[row * CDIM + col] = acc[i][j][r] + bpv[j];
      }
}

extern "C" void kernel_launch(void* const* d_in, const int* in_sizes, int n_in,
                              void* d_out, int out_size, void* d_ws, size_t ws_size,
                              hipStream_t stream) {
  const float* x = (const float*)d_in[0];
  const float* w_qkv = (const float*)d_in[1];
  const float* w_proj = (const float*)d_in[2];
  const float* b_proj = (const float*)d_in[3];
  const float* proj = (const float*)d_in[4];
  float* out = (float*)d_out;

  char* p = (char*)d_ws;
  auto take = [&](size_t bytes) {
    char* r = p;
    p += (bytes + 255) & ~(size_t)255;
    return r;
  };
  u16* xb = (u16*)take(32768UL * 768 * 2);      // 50.33 MB; dead after k0 -> ctx8
  u16* wqkvb = (u16*)take(2304UL * 768 * 2);
  u16* wprojb = (u16*)take(768UL * 768 * 2);
  u16* projb = (u16*)take(256UL * 64 * 2);
  u16* qb = (u16*)take(96UL * 4096 * 64 * 2);   // 50.33 MB
  u16* kb = (u16*)take(96UL * 4096 * 64 * 2);   // 50.33 MB; dead after k3f -> attn
  u16* vT = (u16*)take(96UL * 64 * 4096 * 2);   // 50.33 MB
  float* kpart = (float*)take(96UL * 8 * 256 * 4);
  u32* mk = (u32*)take(256);
  u16* baug = (u16*)take(96UL * 80 * 256 * 2);
  float* bsum = (float*)take(96UL * 80 * 4);
  // stream-ordered aliases
  float* ctx8 = (float*)xb;  // [8][96][64][256] f32 == 50.33 MB exactly
  u16* attn = kb;            // 50.33 MB

  k_init<<<1, 64, 0, stream>>>(mk);
  cvt_bf16<<<(25165824 / 4 + 255) / 256, 256, 0, stream>>>(x, xb, 25165824 / 4);
  cvt_bf16<<<(1769472 / 4 + 255) / 256, 256, 0, stream>>>(w_qkv, wqkvb, 1769472 / 4);
  cvt_bf16<<<(589824 / 4 + 255) / 256, 256, 0, stream>>>(w_proj, wprojb, 589824 / 4);
  cvt_bf16<<<(16384 / 4 + 255) / 256, 256, 0, stream>>>(proj, projb, 16384 / 4);
  k0_qkv<<<dim3(18, 256), 256, 0, stream>>>(xb, wqkvb, qb, kb, vT);
  k2_k1<<<dim3(64, 96), 256, 0, stream>>>(kb, projb, mk);
  k3f<<<dim3(8, 96), 256, 0, stream>>>(kb, vT, projb, mk, ctx8, kpart);
  k3b<<<dim3(96, 5), 256, 0, stream>>>(ctx8, kpart, baug, bsum);
  k2q5<<<dim3(16, 96), 256, 0, stream>>>(qb, projb, baug, bsum, attn);
  k6_proj<<<dim3(6, 256), 256, 0, stream>>>(attn, wprojb, b_proj, out);
}

// Round 9
// 508.989 us; speedup vs baseline: 1.4867x; 1.0786x over previous
//
#include <hip/hip_runtime.h>
#include <hip/hip_bf16.h>

typedef __attribute__((ext_vector_type(4))) float f32x4;
typedef __attribute__((ext_vector_type(8))) short s16x8;
typedef __attribute__((ext_vector_type(4))) float f4v;
typedef __attribute__((ext_vector_type(4))) unsigned short us4;
typedef unsigned short u16;
typedef unsigned int u32;

#define H_ 12
#define NTOK 4096
#define DHEAD 64
#define MFEAT 256
#define CDIM 768

#define NORMALIZER 0.35355339059327373f  /* 64^-0.25 */
#define DIAGSCALE 0.0625f                /* 0.5 * NORMALIZER^2 */
#define RATIO_ 0.0625f                   /* 256^-0.5 */
#define EPS_ 1e-4f

#define MFMA(a, b, c) __builtin_amdgcn_mfma_f32_16x16x32_bf16((a), (b), (c), 0, 0, 0)

__device__ __forceinline__ float bf2f(u16 u) {
  union { float f; u32 v; } x; x.v = ((u32)u) << 16; return x.f;
}
__device__ __forceinline__ u16 f2bf(float f) {
  union { float f; u32 v; } x; x.f = f;
  u32 v = x.v + 0x7FFFu + ((x.v >> 16) & 1u);
  return (u16)(v >> 16);
}
__device__ __forceinline__ u32 fenc(float f) {
  u32 u = __float_as_uint(f);
  return (u & 0x80000000u) ? ~u : (u | 0x80000000u);
}
__device__ __forceinline__ float fdec(u32 k) {
  u32 u = (k & 0x80000000u) ? (k & 0x7fffffffu) : ~k;
  return __uint_as_float(u);
}
__device__ __forceinline__ void glds16(const u16* g, u16* l) {
  __builtin_amdgcn_global_load_lds((const __attribute__((address_space(1))) void*)g,
                                   (__attribute__((address_space(3))) void*)l, 16, 0, 0);
}

// write a wave's staged 64x64 bf16 tile (rows padded to 72) to dst
__device__ __forceinline__ void st_write64(const u16* stw, u16* dst, long ld, int lane) {
  int r0 = lane >> 3, cc = lane & 7;
#pragma unroll
  for (int c = 0; c < 8; ++c) {
    int row = c * 8 + r0;
    s16x8 v = *(const s16x8*)(stw + row * 72 + cc * 8);
    *(s16x8*)(dst + (long)row * ld + cc * 8) = v;
  }
}

// ---------------- fused init + fp32->bf16 converts (block-aligned segments) ----------------
__global__ void cvt_all(const float* __restrict__ x, const float* __restrict__ wq,
                        const float* __restrict__ wp, const float* __restrict__ pj,
                        u16* __restrict__ xb, u16* __restrict__ wqb,
                        u16* __restrict__ wpb, u16* __restrict__ pjb, u32* __restrict__ mk) {
  int b = blockIdx.x;
  if (b == 0 && threadIdx.x < 8) mk[threadIdx.x] = 0u;
  const float* s;
  u16* d;
  int base;
  if (b < 24576)      { s = x;  d = xb;  base = b; }
  else if (b < 26304) { s = wq; d = wqb; base = b - 24576; }
  else if (b < 26880) { s = wp; d = wpb; base = b - 26304; }
  else                { s = pj; d = pjb; base = b - 26880; }
  long i = (long)base * 256 + threadIdx.x;
  f4v v = *(const f4v*)(s + i * 4);
  us4 o;
#pragma unroll
  for (int j = 0; j < 4; ++j) o[j] = f2bf(v[j]);
  *(us4*)(d + i * 4) = o;
}

// ---------------- K0: QKV GEMM, BK=64 glds16, XCD-concentrated panel groups ----------------
// logical group by (M-panel) -> its 18 bx-blocks all map to XCD by%8, dispatched adjacently.
__global__ __launch_bounds__(256) void k0_qkv(const u16* __restrict__ A, const u16* __restrict__ Bm,
                                              u16* __restrict__ qb, u16* __restrict__ kb,
                                              u16* __restrict__ vT) {
  __shared__ u16 smem[4 * 64 * 72];   // loop: lA[0,8192) lB[8192,16384) u16; epilogue: 4x 64x72
  u16* lA = smem;
  u16* lB = smem + 8192;
  int tid = threadIdx.x, lane = tid & 63, wid = tid >> 6;
  // XCD-concentration remap (bijective on [0,4608))
  int p = blockIdx.x + blockIdx.y * 18;
  int r8 = p & 7, q = p >> 3;        // q in [0,576)
  int bx = q % 18;                   // N-panel member
  int by = (q / 18) * 8 + r8;        // M-panel group (same XCD for all 18 members)
  int m0 = by << 7, n0 = bx << 7;
  int wr = (wid >> 1) << 6, wc = (wid & 1) << 6;
  int l15 = lane & 15, lk = lane >> 4;
  int lr = lane >> 3;            // row within 8-row group
  int lu = (lane & 7) ^ lr;      // pre-swizzled source 16B-unit
  const u16* Ab = A + (long)m0 * CDIM;
  const u16* Bb = Bm + (long)n0 * CDIM;
  const u16* gA = Ab + (long)(wid * 32 + lr) * CDIM + lu * 8;
  const u16* gB = Bb + (long)(wid * 32 + lr) * CDIM + lu * 8;
  u16* dA = lA + wid * 2048;
  u16* dB = lB + wid * 2048;
  f32x4 acc[4][4];
#pragma unroll
  for (int i = 0; i < 4; ++i)
#pragma unroll
    for (int j = 0; j < 4; ++j) acc[i][j] = (f32x4){0.f, 0.f, 0.f, 0.f};
  for (int k0 = 0; k0 < CDIM; k0 += 64) {
    __syncthreads();
#pragma unroll
    for (int g = 0; g < 4; ++g) {
      glds16(gA + k0 + (long)g * 8 * CDIM, dA + g * 512);
      glds16(gB + k0 + (long)g * 8 * CDIM, dB + g * 512);
    }
    __syncthreads();
#pragma unroll
    for (int ks = 0; ks < 2; ++ks) {
      s16x8 af[4], bv[4];
#pragma unroll
      for (int i = 0; i < 4; ++i) {
        int co = ((ks * 4 + lk) ^ (l15 & 7)) * 8;   // swizzled read unit
        af[i] = *(const s16x8*)(lA + (wr + i * 16 + l15) * 64 + co);
        bv[i] = *(const s16x8*)(lB + (wc + i * 16 + l15) * 64 + co);
      }
#pragma unroll
      for (int i = 0; i < 4; ++i)
#pragma unroll
        for (int j = 0; j < 4; ++j) acc[i][j] = MFMA(af[i], bv[j], acc[i][j]);
    }
  }
  __syncthreads();  // before reusing smem as epilogue stage
  int colbase = n0 + wc;
  int qi = colbase / CDIM;
  int h = (colbase % CDIM) >> 6;
  int rowbase = m0 + wr;
  int b = rowbase >> 12;
  int nloc = rowbase & (NTOK - 1);
  u16* stw = smem + wid * 4608;
  if (qi < 2) {
#pragma unroll
    for (int i = 0; i < 4; ++i)
#pragma unroll
      for (int j = 0; j < 4; ++j)
#pragma unroll
        for (int r = 0; r < 4; ++r)
          stw[(i * 16 + lk * 4 + r) * 72 + j * 16 + l15] = f2bf(acc[i][j][r]);
    u16* dst = (qi == 0 ? qb : kb) + ((long)(b * H_ + h) * NTOK + nloc) * DHEAD;
    st_write64(stw, dst, DHEAD, lane);
  } else {
    // transposed stage: st[dd][n] (pack 4 r's into one b64)
#pragma unroll
    for (int i = 0; i < 4; ++i)
#pragma unroll
      for (int j = 0; j < 4; ++j) {
        us4 w;
#pragma unroll
        for (int r = 0; r < 4; ++r) w[r] = f2bf(acc[i][j][r]);
        *(us4*)(stw + (j * 16 + l15) * 72 + i * 16 + lk * 4) = w;
      }
    u16* dst = vT + (long)(b * H_ + h) * DHEAD * NTOK + nloc;
    st_write64(stw, dst, NTOK, lane);
  }
}

// ---------------- K2k pass1: global max of k_dash per batch ----------------
__global__ __launch_bounds__(256) void k2_k1(const u16* __restrict__ kb, const u16* __restrict__ projb,
                                             u32* __restrict__ mk) {
  __shared__ float wmax[4];
  int bh = blockIdx.y;
  int n0 = blockIdx.x << 6;
  const u16* Aq = kb + ((long)bh * NTOK + n0) * DHEAD;
  int tid = threadIdx.x, lane = tid & 63, wid = tid >> 6;
  int wc = wid << 6;
  int l15 = lane & 15, lk = lane >> 4;
  f32x4 acc[4][4];
#pragma unroll
  for (int i = 0; i < 4; ++i)
#pragma unroll
    for (int j = 0; j < 4; ++j) acc[i][j] = (f32x4){0.f, 0.f, 0.f, 0.f};
#pragma unroll
  for (int ks = 0; ks < 2; ++ks) {
    s16x8 a[4], bv[4];
#pragma unroll
    for (int i = 0; i < 4; ++i)
      a[i] = *(const s16x8*)(Aq + (long)(i * 16 + l15) * DHEAD + ks * 32 + lk * 8);
#pragma unroll
    for (int j = 0; j < 4; ++j)
      bv[j] = *(const s16x8*)(projb + (long)(wc + j * 16 + l15) * DHEAD + ks * 32 + lk * 8);
#pragma unroll
    for (int i = 0; i < 4; ++i)
#pragma unroll
      for (int j = 0; j < 4; ++j) acc[i][j] = MFMA(a[i], bv[j], acc[i][j]);
  }
  float m = -3.4e38f;
#pragma unroll
  for (int i = 0; i < 4; ++i)
#pragma unroll
    for (int j = 0; j < 4; ++j)
#pragma unroll
      for (int r = 0; r < 4; ++r) m = fmaxf(m, acc[i][j][r]);
  m = fmaxf(m, __shfl_xor(m, 1));
  m = fmaxf(m, __shfl_xor(m, 2));
  m = fmaxf(m, __shfl_xor(m, 4));
  m = fmaxf(m, __shfl_xor(m, 8));
  m = fmaxf(m, __shfl_xor(m, 16));
  m = fmaxf(m, __shfl_xor(m, 32));
  if (lane == 0) wmax[wid] = m;
  __syncthreads();
  if (tid == 0) {
    float mm = fmaxf(fmaxf(wmax[0], wmax[1]), fmaxf(wmax[2], wmax[3])) * NORMALIZER;
    atomicMax(mk + (blockIdx.y / H_), fenc(mm));
  }
}

// ---------------- K3f: fused phi(k) + context = k'^T @ v (512-token chunk, barrier-free) ----------------
// ctx8 layout: [nc][bh][dd][m]  (dd-major, coalesced for k3b)
__global__ __launch_bounds__(256) void k3f(const u16* __restrict__ kb, const u16* __restrict__ vT,
                                           const u16* __restrict__ projb, const u32* __restrict__ mk,
                                           float* __restrict__ ctx8, float* __restrict__ kpart) {
  __shared__ u16 smem[4 * 64 * 72];
  int bh = blockIdx.y, nc = blockIdx.x;  // nc in [0,8)
  int tid = threadIdx.x, lane = tid & 63, wid = tid >> 6;
  int l15 = lane & 15, lk = lane >> 4;
  int wc = wid << 6;
  float mg = fdec(mk[bh / H_]);
  const u16* Kb = kb + ((long)bh * NTOK + nc * 512) * DHEAD;
  const u16* Vb = vT + (long)bh * DHEAD * NTOK + nc * 512;
  u16* ktw = smem + wid * 4608;  // per-wave 9216B tile (wave-local!)
  f32x4 ctxa[4][4];
#pragma unroll
  for (int i = 0; i < 4; ++i)
#pragma unroll
    for (int j = 0; j < 4; ++j) ctxa[i][j] = (f32x4){0.f, 0.f, 0.f, 0.f};
  float cs[4] = {0.f, 0.f, 0.f, 0.f};
  for (int sb = 0; sb < 8; ++sb) {
    const u16* Ksb = Kb + sb * 64 * DHEAD;
    s16x8 a[4][2];
    float ss[4] = {0.f, 0.f, 0.f, 0.f};
#pragma unroll
    for (int i = 0; i < 4; ++i)
#pragma unroll
      for (int ks = 0; ks < 2; ++ks) {
        a[i][ks] = *(const s16x8*)(Ksb + (long)(i * 16 + l15) * DHEAD + ks * 32 + lk * 8);
#pragma unroll
        for (int e = 0; e < 8; ++e) { float f = bf2f((u16)a[i][ks][e]); ss[i] += f * f; }
      }
    float dgv[4];
#pragma unroll
    for (int i = 0; i < 4; ++i) {
      float s = ss[i];
      s += __shfl_xor(s, 16);
      s += __shfl_xor(s, 32);
      dgv[i] = s * DIAGSCALE;  // diag of token 16i+l15 (uniform over lk)
    }
    f32x4 dacc[4][4];
#pragma unroll
    for (int i = 0; i < 4; ++i)
#pragma unroll
      for (int j = 0; j < 4; ++j) dacc[i][j] = (f32x4){0.f, 0.f, 0.f, 0.f};
#pragma unroll
    for (int ks = 0; ks < 2; ++ks)
#pragma unroll
      for (int j = 0; j < 4; ++j) {
        s16x8 pb = *(const s16x8*)(projb + (long)(wc + j * 16 + l15) * DHEAD + ks * 32 + lk * 8);
#pragma unroll
        for (int i = 0; i < 4; ++i) dacc[i][j] = MFMA(a[i][ks], pb, dacc[i][j]);
      }
    // diag at token 16i+4lk+r via shuffle
    float dgr[4][4];
#pragma unroll
    for (int i = 0; i < 4; ++i)
#pragma unroll
      for (int r = 0; r < 4; ++r) dgr[i][r] = __shfl(dgv[i], 4 * lk + r);
    // phi -> kT (wave-local), packed b64 writes
#pragma unroll
    for (int i = 0; i < 4; ++i)
#pragma unroll
      for (int j = 0; j < 4; ++j) {
        us4 w;
#pragma unroll
        for (int r = 0; r < 4; ++r) {
          float v = RATIO_ * (__expf(dacc[i][j][r] * NORMALIZER - dgr[i][r] - mg) + EPS_);
          cs[j] += v;
          w[r] = f2bf(v);
        }
        *(us4*)(ktw + (j * 16 + l15) * 72 + i * 16 + lk * 4) = w;
      }
    // context MFMA: A = k'(features) rows from ktw, B = vT rows
#pragma unroll
    for (int ks = 0; ks < 2; ++ks) {
      s16x8 a2f[4], vb[4];
#pragma unroll
      for (int ii = 0; ii < 4; ++ii)
        a2f[ii] = *(const s16x8*)(ktw + (ii * 16 + l15) * 72 + ks * 32 + lk * 8);
#pragma unroll
      for (int jv = 0; jv < 4; ++jv)
        vb[jv] = *(const s16x8*)(Vb + (long)(jv * 16 + l15) * NTOK + sb * 64 + ks * 32 + lk * 8);
#pragma unroll
      for (int ii = 0; ii < 4; ++ii)
#pragma unroll
        for (int jv = 0; jv < 4; ++jv) ctxa[ii][jv] = MFMA(a2f[ii], vb[jv], ctxa[ii][jv]);
    }
  }
  asm volatile("" ::: "memory");  // fence u16/f32 LDS type-pun reordering
  // epilogue: transpose wave quadrant to [dd][m] via LDS (stride 68 f32), coalesced f32 writes
  float* lf = (float*)ktw;  // 32 x 68 f32 = 8704B <= 9216B
  float* dstb = ctx8 + (long)(nc * 96 + bh) * (MFEAT * DHEAD);
#pragma unroll
  for (int half = 0; half < 2; ++half) {
#pragma unroll
    for (int jh = 0; jh < 2; ++jh) {
      int jv = half * 2 + jh;
#pragma unroll
      for (int ii = 0; ii < 4; ++ii)
        *(f4v*)(lf + (jh * 16 + l15) * 68 + ii * 16 + lk * 4) =
            (f4v){ctxa[ii][jv][0], ctxa[ii][jv][1], ctxa[ii][jv][2], ctxa[ii][jv][3]};
    }
#pragma unroll
    for (int u = 0; u < 8; ++u) {
      int dd_l = u * 4 + lk;
      f4v v = *(const f4v*)(lf + dd_l * 68 + l15 * 4);
      *(f4v*)(dstb + (long)(half * 32 + dd_l) * MFEAT + wc + l15 * 4) = v;
    }
    asm volatile("" ::: "memory");
  }
#pragma unroll
  for (int j = 0; j < 4; ++j) {
    float s = cs[j];
    s += __shfl_xor(s, 16);
    s += __shfl_xor(s, 32);
    if (lk == 0) kpart[((long)bh * 8 + nc) * MFEAT + wc + j * 16 + l15] = s;
  }
}

// ---------------- K3b: Baug[bh][80][256] = [ctx^T ; k_sum ; 0] + f32 row-sums bsum[bh][80] ----------------
__global__ __launch_bounds__(256) void k3b(const float* __restrict__ ctx8, const float* __restrict__ kpart,
                                           u16* __restrict__ baug, float* __restrict__ bsum) {
  int bh = blockIdx.x, y = blockIdx.y;
  int tid = threadIdx.x;
  u16* o = baug + (long)bh * 80 * MFEAT;
  if (y < 4) {
    int dd = y * 16 + (tid >> 4);
    int m0 = (tid & 15) * 16;
    f4v s[4];
#pragma unroll
    for (int e = 0; e < 4; ++e) s[e] = (f4v){0.f, 0.f, 0.f, 0.f};
    for (int c = 0; c < 8; ++c) {
      const float* r = ctx8 + (long)(c * 96 + bh) * (MFEAT * DHEAD) + dd * MFEAT + m0;
#pragma unroll
      for (int e = 0; e < 4; ++e) s[e] += *(const f4v*)(r + e * 4);
    }
    float t = 0.f;
#pragma unroll
    for (int e = 0; e < 4; ++e) {
      us4 w;
#pragma unroll
      for (int q = 0; q < 4; ++q) { t += s[e][q]; w[q] = f2bf(s[e][q]); }
      *(us4*)(o + dd * MFEAT + m0 + e * 4) = w;
    }
    t += __shfl_xor(t, 1); t += __shfl_xor(t, 2); t += __shfl_xor(t, 4); t += __shfl_xor(t, 8);
    if ((tid & 15) == 0) bsum[bh * 80 + dd] = t;
  } else {
    __shared__ float red[4];
    int m = tid;
    float ks = 0.f;
    for (int c = 0; c < 8; ++c) ks += kpart[((long)bh * 8 + c) * MFEAT + m];
    o[64 * MFEAT + m] = f2bf(ks);
    float t = ks;
    t += __shfl_xor(t, 1); t += __shfl_xor(t, 2); t += __shfl_xor(t, 4);
    t += __shfl_xor(t, 8); t += __shfl_xor(t, 16); t += __shfl_xor(t, 32);
    if ((m & 63) == 0) red[m >> 6] = t;
    __syncthreads();
    if (m == 0) bsum[bh * 80 + 64] = red[0] + red[1] + red[2] + red[3];
    for (int dd = 65; dd < 80; ++dd) o[dd * MFEAT + m] = 0;
    if (m < 15) bsum[bh * 80 + 65 + m] = 0.f;
  }
}

// ---------------- K2Q5: fused phi(q) + (q' @ Baug^T), online max, analytic eps ----------------
__global__ __launch_bounds__(256) void k2q5(const u16* __restrict__ qb, const u16* __restrict__ projb,
                                            const u16* __restrict__ baug, const float* __restrict__ bsum,
                                            u16* __restrict__ attn) {
  __shared__ u16 smem[4 * 64 * 72];
  int bh = blockIdx.y;
  int b = bh / H_, h = bh % H_;
  int tid = threadIdx.x, lane = tid & 63, wid = tid >> 6;
  int l15 = lane & 15, lk = lane >> 4;
  int tb = blockIdx.x * 256 + wid * 64;  // wave's 64 tokens
  const u16* Aq = qb + ((long)bh * NTOK + tb) * DHEAD;
  const u16* Bb = baug + (long)bh * 80 * MFEAT;
  u16* qTw = smem + wid * 4608;  // loop: [64 tok][40]; epilogue: [64][72]

  // resident q fragments + diag (token = 16i+l15)
  s16x8 a2[4][2];
  float ssv[4] = {0.f, 0.f, 0.f, 0.f};
#pragma unroll
  for (int i = 0; i < 4; ++i)
#pragma unroll
    for (int ks = 0; ks < 2; ++ks) {
      a2[i][ks] = *(const s16x8*)(Aq + (long)(i * 16 + l15) * DHEAD + ks * 32 + lk * 8);
#pragma unroll
      for (int e = 0; e < 8; ++e) { float f = bf2f((u16)a2[i][ks][e]); ssv[i] += f * f; }
    }
  float dgv[4];
#pragma unroll
  for (int i = 0; i < 4; ++i) {
    float s = ssv[i];
    s += __shfl_xor(s, 16);
    s += __shfl_xor(s, 32);
    dgv[i] = s * DIAGSCALE;
  }
  float rm[4] = {-3.4e38f, -3.4e38f, -3.4e38f, -3.4e38f};
  f32x4 oacc[5][4];  // [baug-frag jo][token-frag i]; row=16jo+4lk+r, col(token)=16i+l15
#pragma unroll
  for (int jo = 0; jo < 5; ++jo)
#pragma unroll
    for (int i = 0; i < 4; ++i) oacc[jo][i] = (f32x4){0.f, 0.f, 0.f, 0.f};

  for (int c = 0; c < 8; ++c) {  // 32-feature chunks
    s16x8 pb[2][2];
#pragma unroll
    for (int j = 0; j < 2; ++j)
#pragma unroll
      for (int ks = 0; ks < 2; ++ks)
        pb[j][ks] = *(const s16x8*)(projb + (long)(c * 32 + j * 16 + l15) * DHEAD + ks * 32 + lk * 8);
    f32x4 dacc[2][4];
#pragma unroll
    for (int j = 0; j < 2; ++j)
#pragma unroll
      for (int i = 0; i < 4; ++i) dacc[j][i] = (f32x4){0.f, 0.f, 0.f, 0.f};
#pragma unroll
    for (int ks = 0; ks < 2; ++ks)
#pragma unroll
      for (int j = 0; j < 2; ++j)
#pragma unroll
        for (int i = 0; i < 4; ++i) dacc[j][i] = MFMA(pb[j][ks], a2[i][ks], dacc[j][i]);
    float fsc[4];
#pragma unroll
    for (int i = 0; i < 4; ++i) {
      float cm = dacc[0][i][0];
      cm = fmaxf(cm, dacc[0][i][1]); cm = fmaxf(cm, dacc[0][i][2]); cm = fmaxf(cm, dacc[0][i][3]);
      cm = fmaxf(cm, dacc[1][i][0]); cm = fmaxf(cm, dacc[1][i][1]);
      cm = fmaxf(cm, dacc[1][i][2]); cm = fmaxf(cm, dacc[1][i][3]);
      cm = fmaxf(cm, __shfl_xor(cm, 16));
      cm = fmaxf(cm, __shfl_xor(cm, 32));
      float rn = fmaxf(rm[i], cm);
      fsc[i] = __expf((rm[i] - rn) * NORMALIZER);
      rm[i] = rn;
    }
#pragma unroll
    for (int jo = 0; jo < 5; ++jo)
#pragma unroll
      for (int i = 0; i < 4; ++i) oacc[jo][i] *= fsc[i];
    // phi (NO eps -- handled analytically) -> wave-local LDS [64 tok][40]
#pragma unroll
    for (int i = 0; i < 4; ++i) {
      float dm = dgv[i] + rm[i] * NORMALIZER;
#pragma unroll
      for (int j = 0; j < 2; ++j) {
        us4 w;
#pragma unroll
        for (int r = 0; r < 4; ++r)
          w[r] = f2bf(RATIO_ * __expf(dacc[j][i][r] * NORMALIZER - dm));
        *(us4*)(qTw + (i * 16 + l15) * 40 + j * 16 + lk * 4) = w;
      }
    }
    s16x8 bB[5], qf[4];
#pragma unroll
    for (int jo = 0; jo < 5; ++jo)
      bB[jo] = *(const s16x8*)(Bb + (long)(jo * 16 + l15) * MFEAT + c * 32 + lk * 8);
#pragma unroll
    for (int i = 0; i < 4; ++i)
      qf[i] = *(const s16x8*)(qTw + (i * 16 + l15) * 40 + lk * 8);
#pragma unroll
    for (int jo = 0; jo < 5; ++jo)
#pragma unroll
      for (int i = 0; i < 4; ++i) oacc[jo][i] = MFMA(bB[jo], qf[i], oacc[jo][i]);
  }
  // analytic eps term: out += ratio*eps*rowsum(Baug[br]) (exact, unaffected by rescale)
#pragma unroll
  for (int jo = 0; jo < 5; ++jo) {
    f4v bs = *(const f4v*)(bsum + (long)bh * 80 + jo * 16 + lk * 4);
#pragma unroll
    for (int i = 0; i < 4; ++i)
#pragma unroll
      for (int r = 0; r < 4; ++r) oacc[jo][i][r] += (RATIO_ * EPS_) * bs[r];
  }
  // epilogue: divide by denominator, stage, write
  u16* stw = qTw;  // stride 72 now
#pragma unroll
  for (int i = 0; i < 4; ++i) {
    float dn = __shfl(oacc[4][i][0], l15);  // token 16i+l15's denom from lane (l15, lk=0)
    float inv = 1.0f / dn;
#pragma unroll
    for (int jo = 0; jo < 4; ++jo) {
      us4 w;
#pragma unroll
      for (int r = 0; r < 4; ++r) w[r] = f2bf(oacc[jo][i][r] * inv);
      *(us4*)(stw + (i * 16 + l15) * 72 + jo * 16 + lk * 4) = w;
    }
  }
  u16* dst = attn + ((long)b * NTOK + tb) * CDIM + h * DHEAD;
  st_write64(stw, dst, CDIM, lane);
}

// ---------------- K6: out = attn @ w_proj^T + b_proj (BK=64, XCD-concentrated, fp32 out) ----------------
__global__ __launch_bounds__(256) void k6_proj(const u16* __restrict__ A, const u16* __restrict__ Bm,
                                               const float* __restrict__ bproj, float* __restrict__ out) {
  __shared__ u16 smem[16384];  // lA[0,8192) lB[8192,16384)
  u16* lA = smem;
  u16* lB = smem + 8192;
  int tid = threadIdx.x, lane = tid & 63, wid = tid >> 6;
  // XCD-concentration remap (bijective on [0,1536))
  int p = blockIdx.x + blockIdx.y * 6;
  int r8 = p & 7, q = p >> 3;        // q in [0,192)
  int bx = q % 6;
  int by = (q / 6) * 8 + r8;
  int m0 = by << 7, n0 = bx << 7;
  int wr = (wid >> 1) << 6, wc = (wid & 1) << 6;
  int l15 = lane & 15, lk = lane >> 4;
  int lr = lane >> 3;
  int lu = (lane & 7) ^ lr;
  const u16* Ab = A + (long)m0 * CDIM;
  const u16* Bb = Bm + (long)n0 * CDIM;
  const u16* gA = Ab + (long)(wid * 32 + lr) * CDIM + lu * 8;
  const u16* gB = Bb + (long)(wid * 32 + lr) * CDIM + lu * 8;
  u16* dA = lA + wid * 2048;
  u16* dB = lB + wid * 2048;
  f32x4 acc[4][4];
#pragma unroll
  for (int i = 0; i < 4; ++i)
#pragma unroll
    for (int j = 0; j < 4; ++j) acc[i][j] = (f32x4){0.f, 0.f, 0.f, 0.f};
  for (int k0 = 0; k0 < CDIM; k0 += 64) {
    __syncthreads();
#pragma unroll
    for (int g = 0; g < 4; ++g) {
      glds16(gA + k0 + (long)g * 8 * CDIM, dA + g * 512);
      glds16(gB + k0 + (long)g * 8 * CDIM, dB + g * 512);
    }
    __syncthreads();
#pragma unroll
    for (int ks = 0; ks < 2; ++ks) {
      s16x8 af[4], bv[4];
#pragma unroll
      for (int i = 0; i < 4; ++i) {
        int co = ((ks * 4 + lk) ^ (l15 & 7)) * 8;
        af[i] = *(const s16x8*)(lA + (wr + i * 16 + l15) * 64 + co);
        bv[i] = *(const s16x8*)(lB + (wc + i * 16 + l15) * 64 + co);
      }
#pragma unroll
      for (int i = 0; i < 4; ++i)
#pragma unroll
        for (int j = 0; j < 4; ++j) acc[i][j] = MFMA(af[i], bv[j], acc[i][j]);
    }
  }
  float bpv[4];
#pragma unroll
  for (int j = 0; j < 4; ++j) bpv[j] = bproj[n0 + wc + j * 16 + l15];
#pragma unroll
  for (int i = 0; i < 4; ++i)
#pragma unroll
    for (int j = 0; j < 4; ++j)
#pragma unroll
      for (int r = 0; r < 4; ++r) {
        long row = m0 + wr + i * 16 + lk * 4 + r;
        int col = n0 + wc + j * 16 + l15;
        out[row * CDIM + col] = acc[i][j][r] + bpv[j];
      }
}

extern "C" void kernel_launch(void* const* d_in, const int* in_sizes, int n_in,
                              void* d_out, int out_size, void* d_ws, size_t ws_size,
                              hipStream_t stream) {
  const float* x = (const float*)d_in[0];
  const float* w_qkv = (const float*)d_in[1];
  const float* w_proj = (const float*)d_in[2];
  const float* b_proj = (const float*)d_in[3];
  const float* proj = (const float*)d_in[4];
  float* out = (float*)d_out;

  char* p = (char*)d_ws;
  auto take = [&](size_t bytes) {
    char* r = p;
    p += (bytes + 255) & ~(size_t)255;
    return r;
  };
  u16* xb = (u16*)take(32768UL * 768 * 2);      // 50.33 MB; dead after k0 -> ctx8
  u16* wqkvb = (u16*)take(2304UL * 768 * 2);
  u16* wprojb = (u16*)take(768UL * 768 * 2);
  u16* projb = (u16*)take(256UL * 64 * 2);
  u16* qb = (u16*)take(96UL * 4096 * 64 * 2);   // 50.33 MB
  u16* kb = (u16*)take(96UL * 4096 * 64 * 2);   // 50.33 MB; dead after k3f -> attn
  u16* vT = (u16*)take(96UL * 64 * 4096 * 2);   // 50.33 MB
  float* kpart = (float*)take(96UL * 8 * 256 * 4);
  u32* mk = (u32*)take(256);
  u16* baug = (u16*)take(96UL * 80 * 256 * 2);
  float* bsum = (float*)take(96UL * 80 * 4);
  // stream-ordered aliases
  float* ctx8 = (float*)xb;  // [8][96][64][256] f32 == 50.33 MB exactly
  u16* attn = kb;            // 50.33 MB

  cvt_all<<<26896, 256, 0, stream>>>(x, w_qkv, w_proj, proj, xb, wqkvb, wprojb, projb, mk);
  k0_qkv<<<dim3(18, 256), 256, 0, stream>>>(xb, wqkvb, qb, kb, vT);
  k2_k1<<<dim3(64, 96), 256, 0, stream>>>(kb, projb, mk);
  k3f<<<dim3(8, 96), 256, 0, stream>>>(kb, vT, projb, mk, ctx8, kpart);
  k3b<<<dim3(96, 5), 256, 0, stream>>>(ctx8, kpart, baug, bsum);
  k2q5<<<dim3(16, 96), 256, 0, stream>>>(qb, projb, baug, bsum, attn);
  k6_proj<<<dim3(6, 256), 256, 0, stream>>>(attn, wprojb, b_proj, out);
}